// Round 13
// baseline (622.111 us; speedup 1.0000x reference)
//
#include <hip/hip_runtime.h>

#define G_   128
#define S_   32
#define N_   32
#define D_   128
#define T_   (G_*S_*N_)    // 131072
#define TO_  (G_*N_)       // 4096
#define E_   1048576
#define EO_  16384
#define NTASK_ 10
#define CAP_ 32            // bucket capacity per node (Poisson(8): P(deg>32) ~ 1e-11)

typedef _Float16 h16;
typedef _Float16 half8 __attribute__((ext_vector_type(8)));
typedef _Float16 half4 __attribute__((ext_vector_type(4)));
typedef float f32x16 __attribute__((ext_vector_type(16)));

// ================= merged setup =================
// grid: [0,8192)        bucketed fill of T edges; partition p = b&7, chunk = b>>3
//       [8192,8208)     bucketed fill of EO edges (16 blocks)
//       [8208,8400)     conv-weight fp16 transpose prep (12 mats x 16 chunks)
//       [8400,8496)     q/k fp16 transpose prep (6 x 16)
//       [8496,12592)    x0 -> fp16 + initial subgraph mean (4096 blocks)
__global__ __launch_bounds__(256) void k_prep(
    const int* __restrict__ ei, const int* __restrict__ oei,
    const float* __restrict__ Wr1, const float* __restrict__ Wn1,
    const float* __restrict__ Wr2, const float* __restrict__ Wn2,
    const float* __restrict__ Wq, const float* __restrict__ Wk,
    const float* __restrict__ x0,
    int* __restrict__ cnt, int* __restrict__ ocnt,
    int* __restrict__ colsrc, int* __restrict__ ocolsrc,
    h16* __restrict__ wt, h16* __restrict__ wqkt,
    h16* __restrict__ xh, h16* __restrict__ subh)
{
    __shared__ float red[8][132];
    int b = blockIdx.x, t = threadIdx.x;
    if (b < 8192) {
        const int p = b & 7;
        const int e0 = (b >> 3) * 1024 + t * 4;
        const int4 d4 = *(const int4*)&ei[E_ + e0];
        const int4 s4 = *(const int4*)&ei[e0];
        #pragma unroll
        for (int j = 0; j < 4; ++j) {
            int d = (&d4.x)[j];
            if ((d >> 14) == p) {
                int pos = atomicAdd(&cnt[d], 1);
                if (pos < CAP_) colsrc[(d << 5) + pos] = (&s4.x)[j];
            }
        }
    } else if (b < 8208) {
        const int e0 = (b - 8192) * 1024 + t * 4;
        const int4 d4 = *(const int4*)&oei[EO_ + e0];
        const int4 s4 = *(const int4*)&oei[e0];
        #pragma unroll
        for (int j = 0; j < 4; ++j) {
            int d = (&d4.x)[j];
            int pos = atomicAdd(&ocnt[d], 1);
            if (pos < CAP_) ocolsrc[(d << 5) + pos] = (&s4.x)[j];
        }
    } else if (b < 8400) {
        int idx = b - 8208, mat = idx >> 4, chunk = idx & 15;
        int arr = mat / 3, layer = mat % 3;
        const float* W = (arr == 0 ? Wr1 : arr == 1 ? Wn1 : arr == 2 ? Wr2 : Wn2) + (size_t)layer * 16384;
        h16* outh = wt + (size_t)mat * 16384;
        int base = chunk * 1024;
        for (int i = t; i < 1024; i += 256) {
            int id = base + i;
            int k = id >> 7, n = id & 127;
            outh[n * 128 + k] = (h16)W[id];
        }
    } else if (b < 8496) {
        int idx = b - 8400, m = idx >> 4, chunk = idx & 15;
        int layer = m >> 1, which = m & 1;
        const float* W = (which ? Wk : Wq) + (size_t)layer * 16384;
        h16* o = wqkt + (size_t)m * 16384;
        int base = chunk * 1024;
        for (int i = t; i < 1024; i += 256) {
            int id = base + i;
            int k = id >> 7, n = id & 127;
            o[n * 128 + k] = (h16)W[id];
        }
    } else {
        int gs = b - 8496;
        int cg = t & 31, rg = t >> 5;
        int c4 = cg * 4;
        float4 ssum = make_float4(0.f, 0.f, 0.f, 0.f);
        for (int n = rg; n < 32; n += 8) {
            size_t tt = (size_t)gs * 32 + n;
            float4 v = *(const float4*)&x0[tt * 128 + c4];
            half4 o; o[0] = (h16)v.x; o[1] = (h16)v.y; o[2] = (h16)v.z; o[3] = (h16)v.w;
            *(half4*)&xh[tt * 128 + c4] = o;
            ssum.x += v.x; ssum.y += v.y; ssum.z += v.z; ssum.w += v.w;
        }
        *(float4*)&red[rg][c4] = ssum;
        __syncthreads();
        if (rg == 0) {
            float4 s = make_float4(0.f, 0.f, 0.f, 0.f);
            #pragma unroll
            for (int r = 0; r < 8; ++r) {
                float4 v = *(float4*)&red[r][c4];
                s.x += v.x; s.y += v.y; s.z += v.z; s.w += v.w;
            }
            const float inv = 1.f / 32.f;
            half4 o; o[0] = (h16)(s.x*inv); o[1] = (h16)(s.y*inv); o[2] = (h16)(s.z*inv); o[3] = (h16)(s.w*inv);
            *(half4*)&subh[(size_t)gs * 128 + c4] = o;
        }
    }
}

// ================= bucketed aggregation (T + TO merged), 2 feature-plane passes (grid.y) =================
__global__ __launch_bounds__(256) void k_agg2(
    const h16* __restrict__ xh, const int* __restrict__ cnt, const int* __restrict__ colsrc,
    h16* __restrict__ agg,
    const h16* __restrict__ xat, const int* __restrict__ ocnt, const int* __restrict__ ocolsrc,
    h16* __restrict__ agg2)
{
    const int bx = blockIdx.x;
    const h16* src; const int* cptr; const int* bsrc; h16* dst; int nid;
    if (bx < 4096) { src = xh;  cptr = cnt;  bsrc = colsrc;  dst = agg;  nid = bx * 32 + (threadIdx.x >> 3); }
    else           { src = xat; cptr = ocnt; bsrc = ocolsrc; dst = agg2; nid = (bx - 4096) * 32 + (threadIdx.x >> 3); }
    const int foff = blockIdx.y * 64 + (threadIdx.x & 7) * 8;
    int n = cptr[nid]; n = (n > CAP_) ? CAP_ : n;
    const int* __restrict__ bucket = bsrc + ((size_t)nid << 5);
    float acc[8] = {0.f,0.f,0.f,0.f,0.f,0.f,0.f,0.f};
    const int n4 = n & ~3;
    int e = 0;
    for (; e < n4; e += 4) {
        int4 s4 = *(const int4*)&bucket[e];
        half8 v0 = *(const half8*)&src[(size_t)s4.x * 128 + foff];
        half8 v1 = *(const half8*)&src[(size_t)s4.y * 128 + foff];
        half8 v2 = *(const half8*)&src[(size_t)s4.z * 128 + foff];
        half8 v3 = *(const half8*)&src[(size_t)s4.w * 128 + foff];
        #pragma unroll
        for (int q = 0; q < 8; ++q)
            acc[q] += ((float)v0[q] + (float)v1[q]) + ((float)v2[q] + (float)v3[q]);
    }
    for (; e < n; ++e) {
        int s = bucket[e];
        half8 v = *(const half8*)&src[(size_t)s * 128 + foff];
        #pragma unroll
        for (int q = 0; q < 8; ++q) acc[q] += (float)v[q];
    }
    half8 o;
    #pragma unroll
    for (int j = 0; j < 8; ++j) o[j] = (h16)acc[j];
    *(half8*)&dst[(size_t)nid * 128 + foff] = o;
}

// ================= per-graph attention: q/k MFMA -> softmax -> head-mean -> x_atten =================
__global__ __launch_bounds__(256) void k_attn(
    const h16* __restrict__ subh, const h16* __restrict__ wqkt_l,
    const float* __restrict__ bql, const float* __restrict__ bkl,
    const h16* __restrict__ xh, float* __restrict__ heat, h16* __restrict__ xat)
{
    __shared__ __align__(16) char smem[25600];
    const int tid = threadIdx.x;
    const int g = blockIdx.x;
    h16* aF = (h16*)smem;                   // 512 frag units x 8 h16 = 8KB
    h16* qkT = (h16*)(smem + 8192);         // [mat][n(128)][34] fp16
    float* attn_s = (float*)smem;           // alias over aF after GEMM phase
    #pragma unroll
    for (int it = 0; it < 2; ++it) {
        int u = tid + it * 256;
        int kq = u >> 6, l = u & 63;
        int m = l & 31, ko = kq * 16 + (l >> 5) * 8;
        *(half8*)&aF[u * 8] = *(const half8*)&subh[((size_t)g * 32 + m) * 128 + ko];
    }
    __syncthreads();
    const int w = tid >> 6, lane = tid & 63, lm = lane & 31, lh = lane >> 5;
    const int mat = w & 1, ntp = (w >> 1) * 2;
    const h16* Wt = wqkt_l + (size_t)mat * 16384;
    const float* bias = mat ? bkl : bql;
    f32x16 a0, a1;
    #pragma unroll
    for (int r = 0; r < 16; ++r) { a0[r] = 0.f; a1[r] = 0.f; }
    #pragma unroll
    for (int kq = 0; kq < 8; ++kq) {
        half8 av = *(half8*)&aF[(kq * 64 + lane) * 8];
        half8 b0 = *(const half8*)&Wt[(size_t)(ntp * 32 + lm) * 128 + kq * 16 + lh * 8];
        half8 b1 = *(const half8*)&Wt[(size_t)((ntp + 1) * 32 + lm) * 128 + kq * 16 + lh * 8];
        a0 = __builtin_amdgcn_mfma_f32_32x32x16_f16(av, b0, a0, 0, 0, 0);
        a1 = __builtin_amdgcn_mfma_f32_32x32x16_f16(av, b1, a1, 0, 0, 0);
    }
    __syncthreads();
    #pragma unroll
    for (int ti = 0; ti < 2; ++ti) {
        int n = (ntp + ti) * 32 + lm;
        float bn = bias[n];
        #pragma unroll
        for (int r = 0; r < 16; ++r) {
            int s = (r & 3) + 8 * (r >> 2) + 4 * lh;
            float v = (ti ? a1[r] : a0[r]) + bn;
            qkT[(mat * 128 + n) * 34 + s] = (h16)v;
        }
    }
    for (int i = tid; i < 1024; i += 256) attn_s[i] = 0.f;
    __syncthreads();
    if (tid < 128) {
        int h = tid >> 5, i = tid & 31;
        float qreg[32];
        #pragma unroll
        for (int d = 0; d < 32; ++d) qreg[d] = (float)qkT[(h * 32 + d) * 34 + i];
        float sc[32];
        const float scale = 0.17677669529663687f; // 1/sqrt(32)
        float mx = -1e30f;
        #pragma unroll
        for (int j = 0; j < 32; ++j) {
            float d = 0.f;
            #pragma unroll
            for (int d0 = 0; d0 < 32; ++d0) d += qreg[d0] * (float)qkT[(128 + h * 32 + d0) * 34 + j];
            d *= scale;
            sc[j] = d;
            mx = fmaxf(mx, d);
        }
        float ssum = 0.f;
        #pragma unroll
        for (int j = 0; j < 32; ++j) { float ee = __expf(sc[j] - mx); sc[j] = ee; ssum += ee; }
        float inv = 0.25f / ssum;  // head-mean folded in
        #pragma unroll
        for (int j = 0; j < 32; ++j) atomicAdd(&attn_s[i * 32 + j], sc[j] * inv);
    }
    __syncthreads();
    if (heat != nullptr && g == 127) {
        for (int idx = tid; idx < 1024; idx += 256) heat[idx] = attn_s[idx];
    }
    {
        int c4 = (tid & 31) * 4;
        int ng = tid >> 5;
        for (int n = ng; n < 32; n += 8) {
            float ax = 0.f, ay = 0.f, az = 0.f, aw = 0.f;
            #pragma unroll
            for (int s = 0; s < 32; ++s) {
                float a = attn_s[s * 32 + n];
                half4 xv = *(const half4*)&xh[(((size_t)g * 32 + s) * 32 + n) * 128 + c4];
                ax += a * (float)xv[0]; ay += a * (float)xv[1];
                az += a * (float)xv[2]; aw += a * (float)xv[3];
            }
            half4 o; o[0] = (h16)ax; o[1] = (h16)ay; o[2] = (h16)az; o[3] = (h16)aw;
            *(half4*)&xat[((size_t)g * 32 + n) * 128 + c4] = o;
        }
    }
}

// ================= merged MFMA GraphConv (T branch | TO branch) + BN stats =================
// Near-barrier-free: A and B fragments loaded directly from global (fragment layout
// row=lane&31, k = kq*16 + (lane>>5)*8). A is block-private (L2-hot), B (32KB weights)
// shared by all blocks (L1/L2-resident). ONE __syncthreads() between the accumulate
// loop and the epilogue: orders (a) LDS stats init before epilogue atomics, and
// (b) all global A-reads before the aliased h1pre/aggh epilogue writes.
__global__ __launch_bounds__(256) void k_convs(
    const h16* __restrict__ xT, const h16* __restrict__ aggT,
    const h16* __restrict__ xO, const h16* __restrict__ aggO,
    const h16* __restrict__ wt, int layer,
    const float* __restrict__ b1l, const float* __restrict__ b2l,
    h16* __restrict__ h1, h16* __restrict__ h2, float* __restrict__ stats)
{
    __shared__ float csum[128], csq[128];
    const int tid = threadIdx.x;
    const h16 *A0, *A1, *W0, *W1; const float* bias; h16* outp; float *gsum, *gsq; size_t row0;
    if (blockIdx.x < 1024) {
        A0 = xT; A1 = aggT;
        W0 = wt + (size_t)(0 * 3 + layer) * 16384;
        W1 = wt + (size_t)(1 * 3 + layer) * 16384;
        bias = b1l; outp = h1; gsum = stats; gsq = stats + 128;
        row0 = (size_t)blockIdx.x * 128;
    } else {
        A0 = xO; A1 = aggO;
        W0 = wt + (size_t)(2 * 3 + layer) * 16384;
        W1 = wt + (size_t)(3 * 3 + layer) * 16384;
        bias = b2l; outp = h2; gsum = stats + 256; gsq = stats + 384;
        row0 = (size_t)(blockIdx.x - 1024) * 128;
    }
    if (tid < 128) { csum[tid] = 0.f; csq[tid] = 0.f; }
    const int w = tid >> 6, lane = tid & 63, lm = lane & 31, lh = lane >> 5;
    const int mbase = (w & 1) * 64, nbase = (w >> 1) * 64;
    f32x16 acc[2][2];
    #pragma unroll
    for (int mi = 0; mi < 2; ++mi)
        #pragma unroll
        for (int ni = 0; ni < 2; ++ni)
            #pragma unroll
            for (int r = 0; r < 16; ++r) acc[mi][ni][r] = 0.f;

    #pragma unroll
    for (int p = 0; p < 2; ++p) {
        const h16* A = p ? A1 : A0;
        const h16* B = p ? W1 : W0;
        const h16* a0p = A + (row0 + mbase + lm) * 128 + lh * 8;
        const h16* a1p = a0p + 32 * 128;
        const h16* b0p = B + (size_t)(nbase + lm) * 128 + lh * 8;
        const h16* b1p = b0p + 32 * 128;
        #pragma unroll
        for (int kq = 0; kq < 8; ++kq) {
            half8 a0 = *(const half8*)(a0p + kq * 16);
            half8 a1 = *(const half8*)(a1p + kq * 16);
            half8 b0 = *(const half8*)(b0p + kq * 16);
            half8 b1 = *(const half8*)(b1p + kq * 16);
            acc[0][0] = __builtin_amdgcn_mfma_f32_32x32x16_f16(a0, b0, acc[0][0], 0, 0, 0);
            acc[0][1] = __builtin_amdgcn_mfma_f32_32x32x16_f16(a0, b1, acc[0][1], 0, 0, 0);
            acc[1][0] = __builtin_amdgcn_mfma_f32_32x32x16_f16(a1, b0, acc[1][0], 0, 0, 0);
            acc[1][1] = __builtin_amdgcn_mfma_f32_32x32x16_f16(a1, b1, acc[1][1], 0, 0, 0);
        }
    }
    __syncthreads();   // all global A-reads + LDS stats init complete before any epilogue write
    #pragma unroll
    for (int ni = 0; ni < 2; ++ni) {
        int col = nbase + ni * 32 + lm;
        float bcol = bias[col];
        float s = 0.f, q = 0.f;
        #pragma unroll
        for (int mi = 0; mi < 2; ++mi) {
            #pragma unroll
            for (int r = 0; r < 16; ++r) {
                int row = mbase + mi * 32 + (r & 3) + 8 * (r >> 2) + 4 * lh;
                float o = acc[mi][ni][r] + bcol;
                outp[(row0 + row) * 128 + col] = (h16)o;
                s += o; q += o * o;
            }
        }
        atomicAdd(&csum[col], s);
        atomicAdd(&csq[col], q);
    }
    __syncthreads();
    if (tid < 128) atomicAdd(&gsum[tid], csum[tid]);
    else           atomicAdd(&gsq[tid - 128], csq[tid - 128]);
}

// ================= x = relu(BN1(h1)+BN2(h2)); fused BN-finalize + next submean =================
__global__ __launch_bounds__(256) void k_update(
    const h16* __restrict__ hpre, const h16* __restrict__ h2pre,
    const float* __restrict__ stats,
    const float* __restrict__ g1, const float* __restrict__ be1,
    const float* __restrict__ g2, const float* __restrict__ be2,
    h16* __restrict__ x, h16* __restrict__ subh)
{
    __shared__ float sA[128], hA[128], sB[128], hB[128];
    __shared__ float red[8][132];
    int gs = blockIdx.x, g = gs >> 5, tid = threadIdx.x;
    if (tid < 128) {
        float mu = stats[tid] * (1.f / T_);
        float var = stats[128 + tid] * (1.f / T_) - mu * mu;
        float sc = g1[tid] * rsqrtf(var + 1e-5f);
        sA[tid] = sc; hA[tid] = be1[tid] - mu * sc;
    } else {
        int c = tid - 128;
        float mu = stats[256 + c] * (1.f / TO_);
        float var = stats[384 + c] * (1.f / TO_) - mu * mu;
        float sc = g2[c] * rsqrtf(var + 1e-5f);
        sB[c] = sc; hB[c] = be2[c] - mu * sc;
    }
    __syncthreads();
    int cg = tid & 31, ng = tid >> 5;
    int c4 = cg * 4;
    float4 ssum = make_float4(0.f, 0.f, 0.f, 0.f);
    for (int n = ng; n < 32; n += 8) {
        size_t t = (size_t)gs * 32 + n;
        half4 h1v = *(const half4*)&hpre[t * 128 + c4];
        half4 h2v = *(const half4*)&h2pre[((size_t)g * 32 + n) * 128 + c4];
        float o0 = fmaxf((float)h1v[0] * sA[c4+0] + hA[c4+0] + (float)h2v[0] * sB[c4+0] + hB[c4+0], 0.f);
        float o1 = fmaxf((float)h1v[1] * sA[c4+1] + hA[c4+1] + (float)h2v[1] * sB[c4+1] + hB[c4+1], 0.f);
        float o2 = fmaxf((float)h1v[2] * sA[c4+2] + hA[c4+2] + (float)h2v[2] * sB[c4+2] + hB[c4+2], 0.f);
        float o3 = fmaxf((float)h1v[3] * sA[c4+3] + hA[c4+3] + (float)h2v[3] * sB[c4+3] + hB[c4+3], 0.f);
        half4 o; o[0] = (h16)o0; o[1] = (h16)o1; o[2] = (h16)o2; o[3] = (h16)o3;
        *(half4*)&x[t * 128 + c4] = o;
        ssum.x += o0; ssum.y += o1; ssum.z += o2; ssum.w += o3;
    }
    *(float4*)&red[ng][c4] = ssum;
    __syncthreads();
    if (ng == 0) {
        float4 s = make_float4(0.f, 0.f, 0.f, 0.f);
        #pragma unroll
        for (int r = 0; r < 8; ++r) {
            float4 v = *(float4*)&red[r][c4];
            s.x += v.x; s.y += v.y; s.z += v.z; s.w += v.w;
        }
        const float inv = 1.f / 32.f;
        half4 o; o[0] = (h16)(s.x*inv); o[1] = (h16)(s.y*inv); o[2] = (h16)(s.z*inv); o[3] = (h16)(s.w*inv);
        *(half4*)&subh[(size_t)gs * 128 + c4] = o;
    }
}

// ================= final head =================
__global__ __launch_bounds__(256) void k_dense(const h16* __restrict__ subh, const float* __restrict__ Wf1,
    const float* __restrict__ bf1, const float* __restrict__ Wf2, const float* __restrict__ bf2,
    float* __restrict__ out)
{
    int g = blockIdx.x, tid = threadIdx.x;
    __shared__ float hgs[128];
    __shared__ float hid[256];
    if (tid < 128) {
        float s = 0.f;
        for (int ss = 0; ss < 32; ++ss) s += (float)subh[((size_t)g * 32 + ss) * 128 + tid];
        hgs[tid] = s * (1.f / 32.f);
    }
    __syncthreads();
    float a = bf1[tid];
    for (int k = 0; k < 128; ++k) a += hgs[k] * Wf1[k * 256 + tid];
    hid[tid] = fmaxf(a, 0.f);
    __syncthreads();
    if (tid < 10) {
        float o = bf2[tid];
        for (int k = 0; k < 256; ++k) o += hid[k] * Wf2[k * 10 + tid];
        out[g * 10 + tid] = o;
    }
}

extern "C" void kernel_launch(void* const* d_in, const int* in_sizes, int n_in,
                              void* d_out, int out_size, void* d_ws, size_t ws_size,
                              hipStream_t stream)
{
    (void)in_sizes; (void)n_in; (void)out_size; (void)ws_size;
    const float* x0  = (const float*)d_in[0];
    const int*   ei  = (const int*)d_in[1];
    const int*   oei = (const int*)d_in[2];
    const float* Wr1 = (const float*)d_in[3];
    const float* Wn1 = (const float*)d_in[4];
    const float* b1  = (const float*)d_in[5];
    const float* g1  = (const float*)d_in[6];
    const float* be1 = (const float*)d_in[7];
    const float* Wr2 = (const float*)d_in[8];
    const float* Wn2 = (const float*)d_in[9];
    const float* b2  = (const float*)d_in[10];
    const float* g2  = (const float*)d_in[11];
    const float* be2 = (const float*)d_in[12];
    const float* Wq  = (const float*)d_in[13];
    const float* bq  = (const float*)d_in[14];
    const float* Wk  = (const float*)d_in[15];
    const float* bk  = (const float*)d_in[16];
    const float* Wf1 = (const float*)d_in[17];
    const float* bf1 = (const float*)d_in[18];
    const float* Wf2 = (const float*)d_in[19];
    const float* bf2 = (const float*)d_in[20];
    float* out = (float*)d_out;

    char* w = (char*)d_ws;
    size_t off = 0;
    auto alloc = [&](size_t bytes) { void* p = w + off; off = (off + bytes + 255) & ~(size_t)255; return p; };
    h16* xh     = (h16*)alloc((size_t)T_ * D_ * 2);
    h16* aggh   = (h16*)alloc((size_t)T_ * D_ * 2);   // aliased as h1pre (reads-before-writes via barrier)
    h16* agg2   = (h16*)alloc((size_t)TO_ * D_ * 2);  // aliased as h2pre
    h16* xat    = (h16*)alloc((size_t)TO_ * D_ * 2);
    h16* wt     = (h16*)alloc((size_t)12 * 16384 * 2);
    h16* wqkt   = (h16*)alloc((size_t)6 * 16384 * 2);
    h16* subh   = (h16*)alloc((size_t)G_ * S_ * D_ * 2);
    // zero-init region: cnt | ocnt | stats(3 layers x 512)
    int* cnt     = (int*)alloc((size_t)(T_ + TO_) * 4 + 1536 * 4);
    int* ocnt    = cnt + T_;
    float* stats = (float*)(cnt + T_ + TO_);
    int* colsrc  = (int*)alloc((size_t)T_ * CAP_ * 4);    // 16 MB buckets
    int* ocolsrc = (int*)alloc((size_t)TO_ * CAP_ * 4);

    h16* h1pre = aggh;
    h16* h2pre = agg2;

    hipMemsetAsync(cnt, 0, (size_t)(T_ + TO_) * 4 + 1536 * 4, stream);
    k_prep<<<12592, 256, 0, stream>>>(ei, oei, Wr1, Wn1, Wr2, Wn2, Wq, Wk, x0,
                                      cnt, ocnt, colsrc, ocolsrc, wt, wqkt, xh, subh);

    for (int i = 0; i < 3; ++i) {
        // attention first: produces xat so the merged gather can do T and TO together
        k_attn<<<G_, 256, 0, stream>>>(subh, wqkt + (size_t)i * 2 * 16384,
            bq + i * D_, bk + i * D_, xh,
            (i == 2) ? (out + G_ * NTASK_) : nullptr, xat);
        k_agg2<<<dim3(4224, 2), 256, 0, stream>>>(xh, cnt, colsrc, aggh,
                                                  xat, ocnt, ocolsrc, agg2);
        k_convs<<<1056, 256, 0, stream>>>(xh, aggh, xat, agg2, wt, i,
            b1 + i * D_, b2 + i * D_, h1pre, h2pre, stats + i * 512);
        k_update<<<G_ * S_, 256, 0, stream>>>(h1pre, h2pre, stats + i * 512,
            g1 + i * D_, be1 + i * D_, g2 + i * D_, be2 + i * D_, xh, subh);
    }
    k_dense<<<G_, 256, 0, stream>>>(subh, Wf1, bf1, Wf2, bf2, out);
}

// Round 14
// 606.594 us; speedup vs baseline: 1.0256x; 1.0256x over previous
//
#include <hip/hip_runtime.h>

#define G_   128
#define S_   32
#define N_   32
#define D_   128
#define T_   (G_*S_*N_)    // 131072
#define TO_  (G_*N_)       // 4096
#define E_   1048576
#define EO_  16384
#define NTASK_ 10
#define CAP_ 32            // bucket capacity per node (Poisson(8): P(deg>32) ~ 1e-11)

typedef _Float16 h16;
typedef _Float16 half8 __attribute__((ext_vector_type(8)));
typedef _Float16 half4 __attribute__((ext_vector_type(4)));
typedef float f32x16 __attribute__((ext_vector_type(16)));

// ================= merged setup =================
// grid: [0,4096)        bucketed fill of T edges; partition p = b&3 (4 passes), chunk = b>>2
//       [4096,4112)     bucketed fill of EO edges (16 blocks)
//       [4112,4304)     conv-weight fp16 transpose prep (12 mats x 16 chunks)
//       [4304,4400)     q/k fp16 transpose prep (6 x 16)
//       [4400,8496)     x0 -> fp16 + initial subgraph mean (4096 blocks)
__global__ __launch_bounds__(256) void k_prep(
    const int* __restrict__ ei, const int* __restrict__ oei,
    const float* __restrict__ Wr1, const float* __restrict__ Wn1,
    const float* __restrict__ Wr2, const float* __restrict__ Wn2,
    const float* __restrict__ Wq, const float* __restrict__ Wk,
    const float* __restrict__ x0,
    int* __restrict__ cnt, int* __restrict__ ocnt,
    int* __restrict__ colsrc, int* __restrict__ ocolsrc,
    h16* __restrict__ wt, h16* __restrict__ wqkt,
    h16* __restrict__ xh, h16* __restrict__ subh)
{
    __shared__ float red[8][132];
    int b = blockIdx.x, t = threadIdx.x;
    if (b < 4096) {
        const int p = b & 3;
        const int e0 = (b >> 2) * 1024 + t * 4;
        const int4 d4 = *(const int4*)&ei[E_ + e0];
        const int4 s4 = *(const int4*)&ei[e0];
        #pragma unroll
        for (int j = 0; j < 4; ++j) {
            int d = (&d4.x)[j];
            if ((d >> 15) == p) {
                int pos = atomicAdd(&cnt[d], 1);
                if (pos < CAP_) colsrc[(d << 5) + pos] = (&s4.x)[j];
            }
        }
    } else if (b < 4112) {
        const int e0 = (b - 4096) * 1024 + t * 4;
        const int4 d4 = *(const int4*)&oei[EO_ + e0];
        const int4 s4 = *(const int4*)&oei[e0];
        #pragma unroll
        for (int j = 0; j < 4; ++j) {
            int d = (&d4.x)[j];
            int pos = atomicAdd(&ocnt[d], 1);
            if (pos < CAP_) ocolsrc[(d << 5) + pos] = (&s4.x)[j];
        }
    } else if (b < 4304) {
        int idx = b - 4112, mat = idx >> 4, chunk = idx & 15;
        int arr = mat / 3, layer = mat % 3;
        const float* W = (arr == 0 ? Wr1 : arr == 1 ? Wn1 : arr == 2 ? Wr2 : Wn2) + (size_t)layer * 16384;
        h16* outh = wt + (size_t)mat * 16384;
        int base = chunk * 1024;
        for (int i = t; i < 1024; i += 256) {
            int id = base + i;
            int k = id >> 7, n = id & 127;
            outh[n * 128 + k] = (h16)W[id];
        }
    } else if (b < 4400) {
        int idx = b - 4304, m = idx >> 4, chunk = idx & 15;
        int layer = m >> 1, which = m & 1;
        const float* W = (which ? Wk : Wq) + (size_t)layer * 16384;
        h16* o = wqkt + (size_t)m * 16384;
        int base = chunk * 1024;
        for (int i = t; i < 1024; i += 256) {
            int id = base + i;
            int k = id >> 7, n = id & 127;
            o[n * 128 + k] = (h16)W[id];
        }
    } else {
        int gs = b - 4400;
        int cg = t & 31, rg = t >> 5;
        int c4 = cg * 4;
        float4 ssum = make_float4(0.f, 0.f, 0.f, 0.f);
        for (int n = rg; n < 32; n += 8) {
            size_t tt = (size_t)gs * 32 + n;
            float4 v = *(const float4*)&x0[tt * 128 + c4];
            half4 o; o[0] = (h16)v.x; o[1] = (h16)v.y; o[2] = (h16)v.z; o[3] = (h16)v.w;
            *(half4*)&xh[tt * 128 + c4] = o;
            ssum.x += v.x; ssum.y += v.y; ssum.z += v.z; ssum.w += v.w;
        }
        *(float4*)&red[rg][c4] = ssum;
        __syncthreads();
        if (rg == 0) {
            float4 s = make_float4(0.f, 0.f, 0.f, 0.f);
            #pragma unroll
            for (int r = 0; r < 8; ++r) {
                float4 v = *(float4*)&red[r][c4];
                s.x += v.x; s.y += v.y; s.z += v.z; s.w += v.w;
            }
            const float inv = 1.f / 32.f;
            half4 o; o[0] = (h16)(s.x*inv); o[1] = (h16)(s.y*inv); o[2] = (h16)(s.z*inv); o[3] = (h16)(s.w*inv);
            *(half4*)&subh[(size_t)gs * 128 + c4] = o;
        }
    }
}

// ================= bucketed aggregation (T + TO merged), 2 feature-plane passes (grid.y) =================
__global__ __launch_bounds__(256) void k_agg2(
    const h16* __restrict__ xh, const int* __restrict__ cnt, const int* __restrict__ colsrc,
    h16* __restrict__ agg,
    const h16* __restrict__ xat, const int* __restrict__ ocnt, const int* __restrict__ ocolsrc,
    h16* __restrict__ agg2)
{
    const int bx = blockIdx.x;
    const h16* src; const int* cptr; const int* bsrc; h16* dst; int nid;
    if (bx < 4096) { src = xh;  cptr = cnt;  bsrc = colsrc;  dst = agg;  nid = bx * 32 + (threadIdx.x >> 3); }
    else           { src = xat; cptr = ocnt; bsrc = ocolsrc; dst = agg2; nid = (bx - 4096) * 32 + (threadIdx.x >> 3); }
    const int foff = blockIdx.y * 64 + (threadIdx.x & 7) * 8;
    int n = cptr[nid]; n = (n > CAP_) ? CAP_ : n;
    const int* __restrict__ bucket = bsrc + ((size_t)nid << 5);
    float acc[8] = {0.f,0.f,0.f,0.f,0.f,0.f,0.f,0.f};
    const int n4 = n & ~3;
    int e = 0;
    for (; e < n4; e += 4) {
        int4 s4 = *(const int4*)&bucket[e];
        half8 v0 = *(const half8*)&src[(size_t)s4.x * 128 + foff];
        half8 v1 = *(const half8*)&src[(size_t)s4.y * 128 + foff];
        half8 v2 = *(const half8*)&src[(size_t)s4.z * 128 + foff];
        half8 v3 = *(const half8*)&src[(size_t)s4.w * 128 + foff];
        #pragma unroll
        for (int q = 0; q < 8; ++q)
            acc[q] += ((float)v0[q] + (float)v1[q]) + ((float)v2[q] + (float)v3[q]);
    }
    for (; e < n; ++e) {
        int s = bucket[e];
        half8 v = *(const half8*)&src[(size_t)s * 128 + foff];
        #pragma unroll
        for (int q = 0; q < 8; ++q) acc[q] += (float)v[q];
    }
    half8 o;
    #pragma unroll
    for (int j = 0; j < 8; ++j) o[j] = (h16)acc[j];
    *(half8*)&dst[(size_t)nid * 128 + foff] = o;
}

// ================= per-graph attention: q/k MFMA -> softmax -> head-mean -> x_atten =================
__global__ __launch_bounds__(256) void k_attn(
    const h16* __restrict__ subh, const h16* __restrict__ wqkt_l,
    const float* __restrict__ bql, const float* __restrict__ bkl,
    const h16* __restrict__ xh, float* __restrict__ heat, h16* __restrict__ xat)
{
    __shared__ __align__(16) char smem[25600];
    const int tid = threadIdx.x;
    const int g = blockIdx.x;
    h16* aF = (h16*)smem;                   // 512 frag units x 8 h16 = 8KB
    h16* qkT = (h16*)(smem + 8192);         // [mat][n(128)][34] fp16
    float* attn_s = (float*)smem;           // alias over aF after GEMM phase
    #pragma unroll
    for (int it = 0; it < 2; ++it) {
        int u = tid + it * 256;
        int kq = u >> 6, l = u & 63;
        int m = l & 31, ko = kq * 16 + (l >> 5) * 8;
        *(half8*)&aF[u * 8] = *(const half8*)&subh[((size_t)g * 32 + m) * 128 + ko];
    }
    __syncthreads();
    const int w = tid >> 6, lane = tid & 63, lm = lane & 31, lh = lane >> 5;
    const int mat = w & 1, ntp = (w >> 1) * 2;
    const h16* Wt = wqkt_l + (size_t)mat * 16384;
    const float* bias = mat ? bkl : bql;
    f32x16 a0, a1;
    #pragma unroll
    for (int r = 0; r < 16; ++r) { a0[r] = 0.f; a1[r] = 0.f; }
    #pragma unroll
    for (int kq = 0; kq < 8; ++kq) {
        half8 av = *(half8*)&aF[(kq * 64 + lane) * 8];
        half8 b0 = *(const half8*)&Wt[(size_t)(ntp * 32 + lm) * 128 + kq * 16 + lh * 8];
        half8 b1 = *(const half8*)&Wt[(size_t)((ntp + 1) * 32 + lm) * 128 + kq * 16 + lh * 8];
        a0 = __builtin_amdgcn_mfma_f32_32x32x16_f16(av, b0, a0, 0, 0, 0);
        a1 = __builtin_amdgcn_mfma_f32_32x32x16_f16(av, b1, a1, 0, 0, 0);
    }
    __syncthreads();
    #pragma unroll
    for (int ti = 0; ti < 2; ++ti) {
        int n = (ntp + ti) * 32 + lm;
        float bn = bias[n];
        #pragma unroll
        for (int r = 0; r < 16; ++r) {
            int s = (r & 3) + 8 * (r >> 2) + 4 * lh;
            float v = (ti ? a1[r] : a0[r]) + bn;
            qkT[(mat * 128 + n) * 34 + s] = (h16)v;
        }
    }
    for (int i = tid; i < 1024; i += 256) attn_s[i] = 0.f;
    __syncthreads();
    if (tid < 128) {
        int h = tid >> 5, i = tid & 31;
        float qreg[32];
        #pragma unroll
        for (int d = 0; d < 32; ++d) qreg[d] = (float)qkT[(h * 32 + d) * 34 + i];
        float sc[32];
        const float scale = 0.17677669529663687f; // 1/sqrt(32)
        float mx = -1e30f;
        #pragma unroll
        for (int j = 0; j < 32; ++j) {
            float d = 0.f;
            #pragma unroll
            for (int d0 = 0; d0 < 32; ++d0) d += qreg[d0] * (float)qkT[(128 + h * 32 + d0) * 34 + j];
            d *= scale;
            sc[j] = d;
            mx = fmaxf(mx, d);
        }
        float ssum = 0.f;
        #pragma unroll
        for (int j = 0; j < 32; ++j) { float ee = __expf(sc[j] - mx); sc[j] = ee; ssum += ee; }
        float inv = 0.25f / ssum;  // head-mean folded in
        #pragma unroll
        for (int j = 0; j < 32; ++j) atomicAdd(&attn_s[i * 32 + j], sc[j] * inv);
    }
    __syncthreads();
    if (heat != nullptr && g == 127) {
        for (int idx = tid; idx < 1024; idx += 256) heat[idx] = attn_s[idx];
    }
    {
        int c4 = (tid & 31) * 4;
        int ng = tid >> 5;
        for (int n = ng; n < 32; n += 8) {
            float ax = 0.f, ay = 0.f, az = 0.f, aw = 0.f;
            #pragma unroll
            for (int s = 0; s < 32; ++s) {
                float a = attn_s[s * 32 + n];
                half4 xv = *(const half4*)&xh[(((size_t)g * 32 + s) * 32 + n) * 128 + c4];
                ax += a * (float)xv[0]; ay += a * (float)xv[1];
                az += a * (float)xv[2]; aw += a * (float)xv[3];
            }
            half4 o; o[0] = (h16)ax; o[1] = (h16)ay; o[2] = (h16)az; o[3] = (h16)aw;
            *(half4*)&xat[((size_t)g * 32 + n) * 128 + c4] = o;
        }
    }
}

// ================= merged MFMA GraphConv (T branch | TO branch) + BN stats =================
__global__ __launch_bounds__(256) void k_convs(
    const h16* __restrict__ xT, const h16* __restrict__ aggT,
    const h16* __restrict__ xO, const h16* __restrict__ aggO,
    const h16* __restrict__ wt, int layer,
    const float* __restrict__ b1l, const float* __restrict__ b2l,
    h16* __restrict__ h1, h16* __restrict__ h2, float* __restrict__ stats)
{
    __shared__ h16 lsA[4096];
    __shared__ h16 lsB[4096];
    __shared__ float csum[128], csq[128];
    const int tid = threadIdx.x;
    const h16 *A0, *A1, *W0, *W1; const float* bias; h16* outp; float *gsum, *gsq; size_t row0;
    if (blockIdx.x < 1024) {
        A0 = xT; A1 = aggT;
        W0 = wt + (size_t)(0 * 3 + layer) * 16384;
        W1 = wt + (size_t)(1 * 3 + layer) * 16384;
        bias = b1l; outp = h1; gsum = stats; gsq = stats + 128;
        row0 = (size_t)blockIdx.x * 128;
    } else {
        A0 = xO; A1 = aggO;
        W0 = wt + (size_t)(2 * 3 + layer) * 16384;
        W1 = wt + (size_t)(3 * 3 + layer) * 16384;
        bias = b2l; outp = h2; gsum = stats + 256; gsq = stats + 384;
        row0 = (size_t)(blockIdx.x - 1024) * 128;
    }
    if (tid < 128) { csum[tid] = 0.f; csq[tid] = 0.f; }
    const int w = tid >> 6, lane = tid & 63, lm = lane & 31, lh = lane >> 5;
    const int mbase = (w & 1) * 64, nbase = (w >> 1) * 64;
    f32x16 acc[2][2];
    #pragma unroll
    for (int mi = 0; mi < 2; ++mi)
        #pragma unroll
        for (int ni = 0; ni < 2; ++ni)
            #pragma unroll
            for (int r = 0; r < 16; ++r) acc[mi][ni][r] = 0.f;

    for (int p = 0; p < 2; ++p) {
        const h16* A = p ? A1 : A0;
        const h16* B = p ? W1 : W0;
        for (int kc = 0; kc < 4; ++kc) {
            __syncthreads();
            #pragma unroll
            for (int it = 0; it < 2; ++it) {
                int u = tid + it * 256;
                int m = u & 127, ch = u >> 7;
                *(half8*)&lsA[u * 8] = *(const half8*)&A[(row0 + m) * 128 + kc * 32 + ch * 8];
                *(half8*)&lsB[u * 8] = *(const half8*)&B[(size_t)m * 128 + kc * 32 + ch * 8];
            }
            __syncthreads();
            #pragma unroll
            for (int c = 0; c < 2; ++c) {
                const int base = (2 * c + lh) * 128;
                half8 a0 = *(half8*)&lsA[(base + mbase + lm) * 8];
                half8 a1 = *(half8*)&lsA[(base + mbase + 32 + lm) * 8];
                half8 b0 = *(half8*)&lsB[(base + nbase + lm) * 8];
                half8 b1 = *(half8*)&lsB[(base + nbase + 32 + lm) * 8];
                acc[0][0] = __builtin_amdgcn_mfma_f32_32x32x16_f16(a0, b0, acc[0][0], 0, 0, 0);
                acc[0][1] = __builtin_amdgcn_mfma_f32_32x32x16_f16(a0, b1, acc[0][1], 0, 0, 0);
                acc[1][0] = __builtin_amdgcn_mfma_f32_32x32x16_f16(a1, b0, acc[1][0], 0, 0, 0);
                acc[1][1] = __builtin_amdgcn_mfma_f32_32x32x16_f16(a1, b1, acc[1][1], 0, 0, 0);
            }
        }
    }
    #pragma unroll
    for (int ni = 0; ni < 2; ++ni) {
        int col = nbase + ni * 32 + lm;
        float bcol = bias[col];
        float s = 0.f, q = 0.f;
        #pragma unroll
        for (int mi = 0; mi < 2; ++mi) {
            #pragma unroll
            for (int r = 0; r < 16; ++r) {
                int row = mbase + mi * 32 + (r & 3) + 8 * (r >> 2) + 4 * lh;
                float o = acc[mi][ni][r] + bcol;
                outp[(row0 + row) * 128 + col] = (h16)o;
                s += o; q += o * o;
            }
        }
        atomicAdd(&csum[col], s);
        atomicAdd(&csq[col], q);
    }
    __syncthreads();
    if (tid < 128) atomicAdd(&gsum[tid], csum[tid]);
    else           atomicAdd(&gsq[tid - 128], csq[tid - 128]);
}

// ================= x = relu(BN1(h1)+BN2(h2)); fused BN-finalize + next submean =================
__global__ __launch_bounds__(256) void k_update(
    const h16* __restrict__ hpre, const h16* __restrict__ h2pre,
    const float* __restrict__ stats,
    const float* __restrict__ g1, const float* __restrict__ be1,
    const float* __restrict__ g2, const float* __restrict__ be2,
    h16* __restrict__ x, h16* __restrict__ subh)
{
    __shared__ float sA[128], hA[128], sB[128], hB[128];
    __shared__ float red[8][132];
    int gs = blockIdx.x, g = gs >> 5, tid = threadIdx.x;
    if (tid < 128) {
        float mu = stats[tid] * (1.f / T_);
        float var = stats[128 + tid] * (1.f / T_) - mu * mu;
        float sc = g1[tid] * rsqrtf(var + 1e-5f);
        sA[tid] = sc; hA[tid] = be1[tid] - mu * sc;
    } else {
        int c = tid - 128;
        float mu = stats[256 + c] * (1.f / TO_);
        float var = stats[384 + c] * (1.f / TO_) - mu * mu;
        float sc = g2[c] * rsqrtf(var + 1e-5f);
        sB[c] = sc; hB[c] = be2[c] - mu * sc;
    }
    __syncthreads();
    int cg = tid & 31, ng = tid >> 5;
    int c4 = cg * 4;
    float4 ssum = make_float4(0.f, 0.f, 0.f, 0.f);
    for (int n = ng; n < 32; n += 8) {
        size_t t = (size_t)gs * 32 + n;
        half4 h1v = *(const half4*)&hpre[t * 128 + c4];
        half4 h2v = *(const half4*)&h2pre[((size_t)g * 32 + n) * 128 + c4];
        float o0 = fmaxf((float)h1v[0] * sA[c4+0] + hA[c4+0] + (float)h2v[0] * sB[c4+0] + hB[c4+0], 0.f);
        float o1 = fmaxf((float)h1v[1] * sA[c4+1] + hA[c4+1] + (float)h2v[1] * sB[c4+1] + hB[c4+1], 0.f);
        float o2 = fmaxf((float)h1v[2] * sA[c4+2] + hA[c4+2] + (float)h2v[2] * sB[c4+2] + hB[c4+2], 0.f);
        float o3 = fmaxf((float)h1v[3] * sA[c4+3] + hA[c4+3] + (float)h2v[3] * sB[c4+3] + hB[c4+3], 0.f);
        half4 o; o[0] = (h16)o0; o[1] = (h16)o1; o[2] = (h16)o2; o[3] = (h16)o3;
        *(half4*)&x[t * 128 + c4] = o;
        ssum.x += o0; ssum.y += o1; ssum.z += o2; ssum.w += o3;
    }
    *(float4*)&red[ng][c4] = ssum;
    __syncthreads();
    if (ng == 0) {
        float4 s = make_float4(0.f, 0.f, 0.f, 0.f);
        #pragma unroll
        for (int r = 0; r < 8; ++r) {
            float4 v = *(float4*)&red[r][c4];
            s.x += v.x; s.y += v.y; s.z += v.z; s.w += v.w;
        }
        const float inv = 1.f / 32.f;
        half4 o; o[0] = (h16)(s.x*inv); o[1] = (h16)(s.y*inv); o[2] = (h16)(s.z*inv); o[3] = (h16)(s.w*inv);
        *(half4*)&subh[(size_t)gs * 128 + c4] = o;
    }
}

// ================= final head =================
__global__ __launch_bounds__(256) void k_dense(const h16* __restrict__ subh, const float* __restrict__ Wf1,
    const float* __restrict__ bf1, const float* __restrict__ Wf2, const float* __restrict__ bf2,
    float* __restrict__ out)
{
    int g = blockIdx.x, tid = threadIdx.x;
    __shared__ float hgs[128];
    __shared__ float hid[256];
    if (tid < 128) {
        float s = 0.f;
        for (int ss = 0; ss < 32; ++ss) s += (float)subh[((size_t)g * 32 + ss) * 128 + tid];
        hgs[tid] = s * (1.f / 32.f);
    }
    __syncthreads();
    float a = bf1[tid];
    for (int k = 0; k < 128; ++k) a += hgs[k] * Wf1[k * 256 + tid];
    hid[tid] = fmaxf(a, 0.f);
    __syncthreads();
    if (tid < 10) {
        float o = bf2[tid];
        for (int k = 0; k < 256; ++k) o += hid[k] * Wf2[k * 10 + tid];
        out[g * 10 + tid] = o;
    }
}

extern "C" void kernel_launch(void* const* d_in, const int* in_sizes, int n_in,
                              void* d_out, int out_size, void* d_ws, size_t ws_size,
                              hipStream_t stream)
{
    (void)in_sizes; (void)n_in; (void)out_size; (void)ws_size;
    const float* x0  = (const float*)d_in[0];
    const int*   ei  = (const int*)d_in[1];
    const int*   oei = (const int*)d_in[2];
    const float* Wr1 = (const float*)d_in[3];
    const float* Wn1 = (const float*)d_in[4];
    const float* b1  = (const float*)d_in[5];
    const float* g1  = (const float*)d_in[6];
    const float* be1 = (const float*)d_in[7];
    const float* Wr2 = (const float*)d_in[8];
    const float* Wn2 = (const float*)d_in[9];
    const float* b2  = (const float*)d_in[10];
    const float* g2  = (const float*)d_in[11];
    const float* be2 = (const float*)d_in[12];
    const float* Wq  = (const float*)d_in[13];
    const float* bq  = (const float*)d_in[14];
    const float* Wk  = (const float*)d_in[15];
    const float* bk  = (const float*)d_in[16];
    const float* Wf1 = (const float*)d_in[17];
    const float* bf1 = (const float*)d_in[18];
    const float* Wf2 = (const float*)d_in[19];
    const float* bf2 = (const float*)d_in[20];
    float* out = (float*)d_out;

    char* w = (char*)d_ws;
    size_t off = 0;
    auto alloc = [&](size_t bytes) { void* p = w + off; off = (off + bytes + 255) & ~(size_t)255; return p; };
    h16* xh     = (h16*)alloc((size_t)T_ * D_ * 2);
    h16* aggh   = (h16*)alloc((size_t)T_ * D_ * 2);   // aliased as h1pre (block-local RAW safe)
    h16* agg2   = (h16*)alloc((size_t)TO_ * D_ * 2);  // aliased as h2pre
    h16* xat    = (h16*)alloc((size_t)TO_ * D_ * 2);
    h16* wt     = (h16*)alloc((size_t)12 * 16384 * 2);
    h16* wqkt   = (h16*)alloc((size_t)6 * 16384 * 2);
    h16* subh   = (h16*)alloc((size_t)G_ * S_ * D_ * 2);
    // zero-init region: cnt | ocnt | stats(3 layers x 512)
    int* cnt     = (int*)alloc((size_t)(T_ + TO_) * 4 + 1536 * 4);
    int* ocnt    = cnt + T_;
    float* stats = (float*)(cnt + T_ + TO_);
    int* colsrc  = (int*)alloc((size_t)T_ * CAP_ * 4);    // 16 MB buckets
    int* ocolsrc = (int*)alloc((size_t)TO_ * CAP_ * 4);

    h16* h1pre = aggh;
    h16* h2pre = agg2;

    hipMemsetAsync(cnt, 0, (size_t)(T_ + TO_) * 4 + 1536 * 4, stream);
    k_prep<<<8496, 256, 0, stream>>>(ei, oei, Wr1, Wn1, Wr2, Wn2, Wq, Wk, x0,
                                     cnt, ocnt, colsrc, ocolsrc, wt, wqkt, xh, subh);

    for (int i = 0; i < 3; ++i) {
        // attention first: produces xat so the merged gather can do T and TO together
        k_attn<<<G_, 256, 0, stream>>>(subh, wqkt + (size_t)i * 2 * 16384,
            bq + i * D_, bk + i * D_, xh,
            (i == 2) ? (out + G_ * NTASK_) : nullptr, xat);
        k_agg2<<<dim3(4224, 2), 256, 0, stream>>>(xh, cnt, colsrc, aggh,
                                                  xat, ocnt, ocolsrc, agg2);
        k_convs<<<1056, 256, 0, stream>>>(xh, aggh, xat, agg2, wt, i,
            b1 + i * D_, b2 + i * D_, h1pre, h2pre, stats + i * 512);
        k_update<<<G_ * S_, 256, 0, stream>>>(h1pre, h2pre, stats + i * 512,
            g1 + i * D_, be1 + i * D_, g2 + i * D_, be2 + i * D_, xh, subh);
    }
    k_dense<<<G_, 256, 0, stream>>>(subh, Wf1, bf1, Wf2, bf2, out);
}

// Round 15
// 583.913 us; speedup vs baseline: 1.0654x; 1.0388x over previous
//
#include <hip/hip_runtime.h>

#define G_   128
#define S_   32
#define N_   32
#define D_   128
#define T_   (G_*S_*N_)    // 131072
#define TO_  (G_*N_)       // 4096
#define E_   1048576
#define EO_  16384
#define NTASK_ 10
#define CAP_ 32            // bucket capacity per node (Poisson(8): P(deg>32) ~ 1e-11)

typedef _Float16 h16;
typedef _Float16 half8 __attribute__((ext_vector_type(8)));
typedef _Float16 half4 __attribute__((ext_vector_type(4)));
typedef float f32x16 __attribute__((ext_vector_type(16)));

// ================= merged setup =================
// grid: [0,8192)        bucketed fill of T edges; partition p = b&7 (8 passes), chunk = b>>3
//       [8192,8208)     bucketed fill of EO edges (16 blocks)
//       [8208,8400)     conv-weight fp16 transpose prep (12 mats x 16 chunks)
//       [8400,8496)     q/k fp16 transpose prep (6 x 16)
//       [8496,12592)    x0 -> fp16 + initial subgraph mean (4096 blocks)
__global__ __launch_bounds__(256) void k_prep(
    const int* __restrict__ ei, const int* __restrict__ oei,
    const float* __restrict__ Wr1, const float* __restrict__ Wn1,
    const float* __restrict__ Wr2, const float* __restrict__ Wn2,
    const float* __restrict__ Wq, const float* __restrict__ Wk,
    const float* __restrict__ x0,
    int* __restrict__ cnt, int* __restrict__ ocnt,
    int* __restrict__ colsrc, int* __restrict__ ocolsrc,
    h16* __restrict__ wt, h16* __restrict__ wqkt,
    h16* __restrict__ xh, h16* __restrict__ subh)
{
    __shared__ float red[8][132];
    int b = blockIdx.x, t = threadIdx.x;
    if (b < 8192) {
        const int p = b & 7;
        const int e0 = (b >> 3) * 1024 + t * 4;
        const int4 d4 = *(const int4*)&ei[E_ + e0];
        const int4 s4 = *(const int4*)&ei[e0];
        #pragma unroll
        for (int j = 0; j < 4; ++j) {
            int d = (&d4.x)[j];
            if ((d >> 14) == p) {
                int pos = atomicAdd(&cnt[d], 1);
                if (pos < CAP_) colsrc[(d << 5) + pos] = (&s4.x)[j];
            }
        }
    } else if (b < 8208) {
        const int e0 = (b - 8192) * 1024 + t * 4;
        const int4 d4 = *(const int4*)&oei[EO_ + e0];
        const int4 s4 = *(const int4*)&oei[e0];
        #pragma unroll
        for (int j = 0; j < 4; ++j) {
            int d = (&d4.x)[j];
            int pos = atomicAdd(&ocnt[d], 1);
            if (pos < CAP_) ocolsrc[(d << 5) + pos] = (&s4.x)[j];
        }
    } else if (b < 8400) {
        int idx = b - 8208, mat = idx >> 4, chunk = idx & 15;
        int arr = mat / 3, layer = mat % 3;
        const float* W = (arr == 0 ? Wr1 : arr == 1 ? Wn1 : arr == 2 ? Wr2 : Wn2) + (size_t)layer * 16384;
        h16* outh = wt + (size_t)mat * 16384;
        int base = chunk * 1024;
        for (int i = t; i < 1024; i += 256) {
            int id = base + i;
            int k = id >> 7, n = id & 127;
            outh[n * 128 + k] = (h16)W[id];
        }
    } else if (b < 8496) {
        int idx = b - 8400, m = idx >> 4, chunk = idx & 15;
        int layer = m >> 1, which = m & 1;
        const float* W = (which ? Wk : Wq) + (size_t)layer * 16384;
        h16* o = wqkt + (size_t)m * 16384;
        int base = chunk * 1024;
        for (int i = t; i < 1024; i += 256) {
            int id = base + i;
            int k = id >> 7, n = id & 127;
            o[n * 128 + k] = (h16)W[id];
        }
    } else {
        int gs = b - 8496;
        int cg = t & 31, rg = t >> 5;
        int c4 = cg * 4;
        float4 ssum = make_float4(0.f, 0.f, 0.f, 0.f);
        for (int n = rg; n < 32; n += 8) {
            size_t tt = (size_t)gs * 32 + n;
            float4 v = *(const float4*)&x0[tt * 128 + c4];
            half4 o; o[0] = (h16)v.x; o[1] = (h16)v.y; o[2] = (h16)v.z; o[3] = (h16)v.w;
            *(half4*)&xh[tt * 128 + c4] = o;
            ssum.x += v.x; ssum.y += v.y; ssum.z += v.z; ssum.w += v.w;
        }
        *(float4*)&red[rg][c4] = ssum;
        __syncthreads();
        if (rg == 0) {
            float4 s = make_float4(0.f, 0.f, 0.f, 0.f);
            #pragma unroll
            for (int r = 0; r < 8; ++r) {
                float4 v = *(float4*)&red[r][c4];
                s.x += v.x; s.y += v.y; s.z += v.z; s.w += v.w;
            }
            const float inv = 1.f / 32.f;
            half4 o; o[0] = (h16)(s.x*inv); o[1] = (h16)(s.y*inv); o[2] = (h16)(s.z*inv); o[3] = (h16)(s.w*inv);
            *(half4*)&subh[(size_t)gs * 128 + c4] = o;
        }
    }
}

// ================= bucketed aggregation (T + TO merged), SINGLE pass, full row =================
// 16 nodes/block, 16 lanes x half8 = full 256B row per node; bucket ints read once.
// blocks [0,8192): T gather from xh; [8192,8448): TO gather from xat.
__global__ __launch_bounds__(256) void k_agg2(
    const h16* __restrict__ xh, const int* __restrict__ cnt, const int* __restrict__ colsrc,
    h16* __restrict__ agg,
    const h16* __restrict__ xat, const int* __restrict__ ocnt, const int* __restrict__ ocolsrc,
    h16* __restrict__ agg2)
{
    const int bx = blockIdx.x;
    const h16* src; const int* cptr; const int* bsrc; h16* dst; int nid;
    if (bx < 8192) { src = xh;  cptr = cnt;  bsrc = colsrc;  dst = agg;  nid = bx * 16 + (threadIdx.x >> 4); }
    else           { src = xat; cptr = ocnt; bsrc = ocolsrc; dst = agg2; nid = (bx - 8192) * 16 + (threadIdx.x >> 4); }
    const int foff = (threadIdx.x & 15) * 8;
    int n = cptr[nid]; n = (n > CAP_) ? CAP_ : n;
    const int* __restrict__ bucket = bsrc + ((size_t)nid << 5);
    float acc[8] = {0.f,0.f,0.f,0.f,0.f,0.f,0.f,0.f};
    const int n4 = n & ~3;
    int e = 0;
    for (; e < n4; e += 4) {
        int4 s4 = *(const int4*)&bucket[e];
        half8 v0 = *(const half8*)&src[(size_t)s4.x * 128 + foff];
        half8 v1 = *(const half8*)&src[(size_t)s4.y * 128 + foff];
        half8 v2 = *(const half8*)&src[(size_t)s4.z * 128 + foff];
        half8 v3 = *(const half8*)&src[(size_t)s4.w * 128 + foff];
        #pragma unroll
        for (int q = 0; q < 8; ++q)
            acc[q] += ((float)v0[q] + (float)v1[q]) + ((float)v2[q] + (float)v3[q]);
    }
    for (; e < n; ++e) {
        int s = bucket[e];
        half8 v = *(const half8*)&src[(size_t)s * 128 + foff];
        #pragma unroll
        for (int q = 0; q < 8; ++q) acc[q] += (float)v[q];
    }
    half8 o;
    #pragma unroll
    for (int j = 0; j < 8; ++j) o[j] = (h16)acc[j];
    *(half8*)&dst[(size_t)nid * 128 + foff] = o;
}

// ================= per-graph attention: q/k MFMA -> softmax -> head-mean -> x_atten =================
__global__ __launch_bounds__(256) void k_attn(
    const h16* __restrict__ subh, const h16* __restrict__ wqkt_l,
    const float* __restrict__ bql, const float* __restrict__ bkl,
    const h16* __restrict__ xh, float* __restrict__ heat, h16* __restrict__ xat)
{
    __shared__ __align__(16) char smem[25600];
    const int tid = threadIdx.x;
    const int g = blockIdx.x;
    h16* aF = (h16*)smem;                   // 512 frag units x 8 h16 = 8KB
    h16* qkT = (h16*)(smem + 8192);         // [mat][n(128)][34] fp16
    float* attn_s = (float*)smem;           // alias over aF after GEMM phase
    #pragma unroll
    for (int it = 0; it < 2; ++it) {
        int u = tid + it * 256;
        int kq = u >> 6, l = u & 63;
        int m = l & 31, ko = kq * 16 + (l >> 5) * 8;
        *(half8*)&aF[u * 8] = *(const half8*)&subh[((size_t)g * 32 + m) * 128 + ko];
    }
    __syncthreads();
    const int w = tid >> 6, lane = tid & 63, lm = lane & 31, lh = lane >> 5;
    const int mat = w & 1, ntp = (w >> 1) * 2;
    const h16* Wt = wqkt_l + (size_t)mat * 16384;
    const float* bias = mat ? bkl : bql;
    f32x16 a0, a1;
    #pragma unroll
    for (int r = 0; r < 16; ++r) { a0[r] = 0.f; a1[r] = 0.f; }
    #pragma unroll
    for (int kq = 0; kq < 8; ++kq) {
        half8 av = *(half8*)&aF[(kq * 64 + lane) * 8];
        half8 b0 = *(const half8*)&Wt[(size_t)(ntp * 32 + lm) * 128 + kq * 16 + lh * 8];
        half8 b1 = *(const half8*)&Wt[(size_t)((ntp + 1) * 32 + lm) * 128 + kq * 16 + lh * 8];
        a0 = __builtin_amdgcn_mfma_f32_32x32x16_f16(av, b0, a0, 0, 0, 0);
        a1 = __builtin_amdgcn_mfma_f32_32x32x16_f16(av, b1, a1, 0, 0, 0);
    }
    __syncthreads();
    #pragma unroll
    for (int ti = 0; ti < 2; ++ti) {
        int n = (ntp + ti) * 32 + lm;
        float bn = bias[n];
        #pragma unroll
        for (int r = 0; r < 16; ++r) {
            int s = (r & 3) + 8 * (r >> 2) + 4 * lh;
            float v = (ti ? a1[r] : a0[r]) + bn;
            qkT[(mat * 128 + n) * 34 + s] = (h16)v;
        }
    }
    for (int i = tid; i < 1024; i += 256) attn_s[i] = 0.f;
    __syncthreads();
    if (tid < 128) {
        int h = tid >> 5, i = tid & 31;
        float qreg[32];
        #pragma unroll
        for (int d = 0; d < 32; ++d) qreg[d] = (float)qkT[(h * 32 + d) * 34 + i];
        float sc[32];
        const float scale = 0.17677669529663687f; // 1/sqrt(32)
        float mx = -1e30f;
        #pragma unroll
        for (int j = 0; j < 32; ++j) {
            float d = 0.f;
            #pragma unroll
            for (int d0 = 0; d0 < 32; ++d0) d += qreg[d0] * (float)qkT[(128 + h * 32 + d0) * 34 + j];
            d *= scale;
            sc[j] = d;
            mx = fmaxf(mx, d);
        }
        float ssum = 0.f;
        #pragma unroll
        for (int j = 0; j < 32; ++j) { float ee = __expf(sc[j] - mx); sc[j] = ee; ssum += ee; }
        float inv = 0.25f / ssum;  // head-mean folded in
        #pragma unroll
        for (int j = 0; j < 32; ++j) atomicAdd(&attn_s[i * 32 + j], sc[j] * inv);
    }
    __syncthreads();
    if (heat != nullptr && g == 127) {
        for (int idx = tid; idx < 1024; idx += 256) heat[idx] = attn_s[idx];
    }
    {
        int c4 = (tid & 31) * 4;
        int ng = tid >> 5;
        for (int n = ng; n < 32; n += 8) {
            float ax = 0.f, ay = 0.f, az = 0.f, aw = 0.f;
            #pragma unroll
            for (int s = 0; s < 32; ++s) {
                float a = attn_s[s * 32 + n];
                half4 xv = *(const half4*)&xh[(((size_t)g * 32 + s) * 32 + n) * 128 + c4];
                ax += a * (float)xv[0]; ay += a * (float)xv[1];
                az += a * (float)xv[2]; aw += a * (float)xv[3];
            }
            half4 o; o[0] = (h16)ax; o[1] = (h16)ay; o[2] = (h16)az; o[3] = (h16)aw;
            *(half4*)&xat[((size_t)g * 32 + n) * 128 + c4] = o;
        }
    }
}

// ================= merged MFMA GraphConv (T branch | TO branch) + BN stats =================
__global__ __launch_bounds__(256) void k_convs(
    const h16* __restrict__ xT, const h16* __restrict__ aggT,
    const h16* __restrict__ xO, const h16* __restrict__ aggO,
    const h16* __restrict__ wt, int layer,
    const float* __restrict__ b1l, const float* __restrict__ b2l,
    h16* __restrict__ h1, h16* __restrict__ h2, float* __restrict__ stats)
{
    __shared__ h16 lsA[4096];
    __shared__ h16 lsB[4096];
    __shared__ float csum[128], csq[128];
    const int tid = threadIdx.x;
    const h16 *A0, *A1, *W0, *W1; const float* bias; h16* outp; float *gsum, *gsq; size_t row0;
    if (blockIdx.x < 1024) {
        A0 = xT; A1 = aggT;
        W0 = wt + (size_t)(0 * 3 + layer) * 16384;
        W1 = wt + (size_t)(1 * 3 + layer) * 16384;
        bias = b1l; outp = h1; gsum = stats; gsq = stats + 128;
        row0 = (size_t)blockIdx.x * 128;
    } else {
        A0 = xO; A1 = aggO;
        W0 = wt + (size_t)(2 * 3 + layer) * 16384;
        W1 = wt + (size_t)(3 * 3 + layer) * 16384;
        bias = b2l; outp = h2; gsum = stats + 256; gsq = stats + 384;
        row0 = (size_t)(blockIdx.x - 1024) * 128;
    }
    if (tid < 128) { csum[tid] = 0.f; csq[tid] = 0.f; }
    const int w = tid >> 6, lane = tid & 63, lm = lane & 31, lh = lane >> 5;
    const int mbase = (w & 1) * 64, nbase = (w >> 1) * 64;
    f32x16 acc[2][2];
    #pragma unroll
    for (int mi = 0; mi < 2; ++mi)
        #pragma unroll
        for (int ni = 0; ni < 2; ++ni)
            #pragma unroll
            for (int r = 0; r < 16; ++r) acc[mi][ni][r] = 0.f;

    for (int p = 0; p < 2; ++p) {
        const h16* A = p ? A1 : A0;
        const h16* B = p ? W1 : W0;
        for (int kc = 0; kc < 4; ++kc) {
            __syncthreads();
            #pragma unroll
            for (int it = 0; it < 2; ++it) {
                int u = tid + it * 256;
                int m = u & 127, ch = u >> 7;
                *(half8*)&lsA[u * 8] = *(const half8*)&A[(row0 + m) * 128 + kc * 32 + ch * 8];
                *(half8*)&lsB[u * 8] = *(const half8*)&B[(size_t)m * 128 + kc * 32 + ch * 8];
            }
            __syncthreads();
            #pragma unroll
            for (int c = 0; c < 2; ++c) {
                const int base = (2 * c + lh) * 128;
                half8 a0 = *(half8*)&lsA[(base + mbase + lm) * 8];
                half8 a1 = *(half8*)&lsA[(base + mbase + 32 + lm) * 8];
                half8 b0 = *(half8*)&lsB[(base + nbase + lm) * 8];
                half8 b1 = *(half8*)&lsB[(base + nbase + 32 + lm) * 8];
                acc[0][0] = __builtin_amdgcn_mfma_f32_32x32x16_f16(a0, b0, acc[0][0], 0, 0, 0);
                acc[0][1] = __builtin_amdgcn_mfma_f32_32x32x16_f16(a0, b1, acc[0][1], 0, 0, 0);
                acc[1][0] = __builtin_amdgcn_mfma_f32_32x32x16_f16(a1, b0, acc[1][0], 0, 0, 0);
                acc[1][1] = __builtin_amdgcn_mfma_f32_32x32x16_f16(a1, b1, acc[1][1], 0, 0, 0);
            }
        }
    }
    #pragma unroll
    for (int ni = 0; ni < 2; ++ni) {
        int col = nbase + ni * 32 + lm;
        float bcol = bias[col];
        float s = 0.f, q = 0.f;
        #pragma unroll
        for (int mi = 0; mi < 2; ++mi) {
            #pragma unroll
            for (int r = 0; r < 16; ++r) {
                int row = mbase + mi * 32 + (r & 3) + 8 * (r >> 2) + 4 * lh;
                float o = acc[mi][ni][r] + bcol;
                outp[(row0 + row) * 128 + col] = (h16)o;
                s += o; q += o * o;
            }
        }
        atomicAdd(&csum[col], s);
        atomicAdd(&csq[col], q);
    }
    __syncthreads();
    if (tid < 128) atomicAdd(&gsum[tid], csum[tid]);
    else           atomicAdd(&gsq[tid - 128], csq[tid - 128]);
}

// ================= x = relu(BN1(h1)+BN2(h2)); fused BN-finalize + next submean =================
__global__ __launch_bounds__(256) void k_update(
    const h16* __restrict__ hpre, const h16* __restrict__ h2pre,
    const float* __restrict__ stats,
    const float* __restrict__ g1, const float* __restrict__ be1,
    const float* __restrict__ g2, const float* __restrict__ be2,
    h16* __restrict__ x, h16* __restrict__ subh)
{
    __shared__ float sA[128], hA[128], sB[128], hB[128];
    __shared__ float red[8][132];
    int gs = blockIdx.x, g = gs >> 5, tid = threadIdx.x;
    if (tid < 128) {
        float mu = stats[tid] * (1.f / T_);
        float var = stats[128 + tid] * (1.f / T_) - mu * mu;
        float sc = g1[tid] * rsqrtf(var + 1e-5f);
        sA[tid] = sc; hA[tid] = be1[tid] - mu * sc;
    } else {
        int c = tid - 128;
        float mu = stats[256 + c] * (1.f / TO_);
        float var = stats[384 + c] * (1.f / TO_) - mu * mu;
        float sc = g2[c] * rsqrtf(var + 1e-5f);
        sB[c] = sc; hB[c] = be2[c] - mu * sc;
    }
    __syncthreads();
    int cg = tid & 31, ng = tid >> 5;
    int c4 = cg * 4;
    float4 ssum = make_float4(0.f, 0.f, 0.f, 0.f);
    for (int n = ng; n < 32; n += 8) {
        size_t t = (size_t)gs * 32 + n;
        half4 h1v = *(const half4*)&hpre[t * 128 + c4];
        half4 h2v = *(const half4*)&h2pre[((size_t)g * 32 + n) * 128 + c4];
        float o0 = fmaxf((float)h1v[0] * sA[c4+0] + hA[c4+0] + (float)h2v[0] * sB[c4+0] + hB[c4+0], 0.f);
        float o1 = fmaxf((float)h1v[1] * sA[c4+1] + hA[c4+1] + (float)h2v[1] * sB[c4+1] + hB[c4+1], 0.f);
        float o2 = fmaxf((float)h1v[2] * sA[c4+2] + hA[c4+2] + (float)h2v[2] * sB[c4+2] + hB[c4+2], 0.f);
        float o3 = fmaxf((float)h1v[3] * sA[c4+3] + hA[c4+3] + (float)h2v[3] * sB[c4+3] + hB[c4+3], 0.f);
        half4 o; o[0] = (h16)o0; o[1] = (h16)o1; o[2] = (h16)o2; o[3] = (h16)o3;
        *(half4*)&x[t * 128 + c4] = o;
        ssum.x += o0; ssum.y += o1; ssum.z += o2; ssum.w += o3;
    }
    *(float4*)&red[ng][c4] = ssum;
    __syncthreads();
    if (ng == 0) {
        float4 s = make_float4(0.f, 0.f, 0.f, 0.f);
        #pragma unroll
        for (int r = 0; r < 8; ++r) {
            float4 v = *(float4*)&red[r][c4];
            s.x += v.x; s.y += v.y; s.z += v.z; s.w += v.w;
        }
        const float inv = 1.f / 32.f;
        half4 o; o[0] = (h16)(s.x*inv); o[1] = (h16)(s.y*inv); o[2] = (h16)(s.z*inv); o[3] = (h16)(s.w*inv);
        *(half4*)&subh[(size_t)gs * 128 + c4] = o;
    }
}

// ================= final head =================
__global__ __launch_bounds__(256) void k_dense(const h16* __restrict__ subh, const float* __restrict__ Wf1,
    const float* __restrict__ bf1, const float* __restrict__ Wf2, const float* __restrict__ bf2,
    float* __restrict__ out)
{
    int g = blockIdx.x, tid = threadIdx.x;
    __shared__ float hgs[128];
    __shared__ float hid[256];
    if (tid < 128) {
        float s = 0.f;
        for (int ss = 0; ss < 32; ++ss) s += (float)subh[((size_t)g * 32 + ss) * 128 + tid];
        hgs[tid] = s * (1.f / 32.f);
    }
    __syncthreads();
    float a = bf1[tid];
    for (int k = 0; k < 128; ++k) a += hgs[k] * Wf1[k * 256 + tid];
    hid[tid] = fmaxf(a, 0.f);
    __syncthreads();
    if (tid < 10) {
        float o = bf2[tid];
        for (int k = 0; k < 256; ++k) o += hid[k] * Wf2[k * 10 + tid];
        out[g * 10 + tid] = o;
    }
}

extern "C" void kernel_launch(void* const* d_in, const int* in_sizes, int n_in,
                              void* d_out, int out_size, void* d_ws, size_t ws_size,
                              hipStream_t stream)
{
    (void)in_sizes; (void)n_in; (void)out_size; (void)ws_size;
    const float* x0  = (const float*)d_in[0];
    const int*   ei  = (const int*)d_in[1];
    const int*   oei = (const int*)d_in[2];
    const float* Wr1 = (const float*)d_in[3];
    const float* Wn1 = (const float*)d_in[4];
    const float* b1  = (const float*)d_in[5];
    const float* g1  = (const float*)d_in[6];
    const float* be1 = (const float*)d_in[7];
    const float* Wr2 = (const float*)d_in[8];
    const float* Wn2 = (const float*)d_in[9];
    const float* b2  = (const float*)d_in[10];
    const float* g2  = (const float*)d_in[11];
    const float* be2 = (const float*)d_in[12];
    const float* Wq  = (const float*)d_in[13];
    const float* bq  = (const float*)d_in[14];
    const float* Wk  = (const float*)d_in[15];
    const float* bk  = (const float*)d_in[16];
    const float* Wf1 = (const float*)d_in[17];
    const float* bf1 = (const float*)d_in[18];
    const float* Wf2 = (const float*)d_in[19];
    const float* bf2 = (const float*)d_in[20];
    float* out = (float*)d_out;

    char* w = (char*)d_ws;
    size_t off = 0;
    auto alloc = [&](size_t bytes) { void* p = w + off; off = (off + bytes + 255) & ~(size_t)255; return p; };
    h16* xh     = (h16*)alloc((size_t)T_ * D_ * 2);
    h16* aggh   = (h16*)alloc((size_t)T_ * D_ * 2);   // aliased as h1pre (block-local RAW safe)
    h16* agg2   = (h16*)alloc((size_t)TO_ * D_ * 2);  // aliased as h2pre
    h16* xat    = (h16*)alloc((size_t)TO_ * D_ * 2);
    h16* wt     = (h16*)alloc((size_t)12 * 16384 * 2);
    h16* wqkt   = (h16*)alloc((size_t)6 * 16384 * 2);
    h16* subh   = (h16*)alloc((size_t)G_ * S_ * D_ * 2);
    // zero-init region: cnt | ocnt | stats(3 layers x 512)
    int* cnt     = (int*)alloc((size_t)(T_ + TO_) * 4 + 1536 * 4);
    int* ocnt    = cnt + T_;
    float* stats = (float*)(cnt + T_ + TO_);
    int* colsrc  = (int*)alloc((size_t)T_ * CAP_ * 4);    // 16 MB buckets
    int* ocolsrc = (int*)alloc((size_t)TO_ * CAP_ * 4);

    h16* h1pre = aggh;
    h16* h2pre = agg2;

    hipMemsetAsync(cnt, 0, (size_t)(T_ + TO_) * 4 + 1536 * 4, stream);
    k_prep<<<12592, 256, 0, stream>>>(ei, oei, Wr1, Wn1, Wr2, Wn2, Wq, Wk, x0,
                                      cnt, ocnt, colsrc, ocolsrc, wt, wqkt, xh, subh);

    for (int i = 0; i < 3; ++i) {
        // attention first: produces xat so the merged gather can do T and TO together
        k_attn<<<G_, 256, 0, stream>>>(subh, wqkt + (size_t)i * 2 * 16384,
            bq + i * D_, bk + i * D_, xh,
            (i == 2) ? (out + G_ * NTASK_) : nullptr, xat);
        k_agg2<<<8448, 256, 0, stream>>>(xh, cnt, colsrc, aggh,
                                         xat, ocnt, ocolsrc, agg2);
        k_convs<<<1056, 256, 0, stream>>>(xh, aggh, xat, agg2, wt, i,
            b1 + i * D_, b2 + i * D_, h1pre, h2pre, stats + i * 512);
        k_update<<<G_ * S_, 256, 0, stream>>>(h1pre, h2pre, stats + i * 512,
            g1 + i * D_, be1 + i * D_, g2 + i * D_, be2 + i * D_, xh, subh);
    }
    k_dense<<<G_, 256, 0, stream>>>(subh, Wf1, bf1, Wf2, bf2, out);
}

// Round 16
// 568.378 us; speedup vs baseline: 1.0945x; 1.0273x over previous
//
#include <hip/hip_runtime.h>

#define G_   128
#define S_   32
#define N_   32
#define D_   128
#define T_   (G_*S_*N_)    // 131072
#define TO_  (G_*N_)       // 4096
#define E_   1048576
#define EO_  16384
#define NTASK_ 10
#define CAP_ 32            // bucket capacity per node (Poisson(8): P(deg>32) ~ 1e-11)

typedef _Float16 h16;
typedef _Float16 half8 __attribute__((ext_vector_type(8)));
typedef _Float16 half4 __attribute__((ext_vector_type(4)));
typedef float f32x16 __attribute__((ext_vector_type(16)));

// ================= merged setup =================
// grid: [0,1024)       bucketed fill of T edges; chunk = b, registers hold edges, loop p=0..7
//                      (co-resident blocks stay softly phase-aligned per partition)
//       [1024,1040)    bucketed fill of EO edges (16 blocks)
//       [1040,1232)    conv-weight fp16 transpose prep (12 mats x 16 chunks)
//       [1232,1328)    q/k fp16 transpose prep (6 x 16)
//       [1328,5424)    x0 -> fp16 + initial subgraph mean (4096 blocks)
__global__ __launch_bounds__(256) void k_prep(
    const int* __restrict__ ei, const int* __restrict__ oei,
    const float* __restrict__ Wr1, const float* __restrict__ Wn1,
    const float* __restrict__ Wr2, const float* __restrict__ Wn2,
    const float* __restrict__ Wq, const float* __restrict__ Wk,
    const float* __restrict__ x0,
    int* __restrict__ cnt, int* __restrict__ ocnt,
    int* __restrict__ colsrc, int* __restrict__ ocolsrc,
    h16* __restrict__ wt, h16* __restrict__ wqkt,
    h16* __restrict__ xh, h16* __restrict__ subh)
{
    __shared__ float red[8][132];
    int b = blockIdx.x, t = threadIdx.x;
    if (b < 1024) {
        const int e0 = b * 1024 + t * 4;
        const int4 d4 = *(const int4*)&ei[E_ + e0];
        const int4 s4 = *(const int4*)&ei[e0];
        #pragma unroll 1
        for (int p = 0; p < 8; ++p) {
            #pragma unroll
            for (int j = 0; j < 4; ++j) {
                int d = (&d4.x)[j];
                if ((d >> 14) == p) {
                    int pos = atomicAdd(&cnt[d], 1);
                    if (pos < CAP_) colsrc[(d << 5) + pos] = (&s4.x)[j];
                }
            }
        }
    } else if (b < 1040) {
        const int e0 = (b - 1024) * 1024 + t * 4;
        const int4 d4 = *(const int4*)&oei[EO_ + e0];
        const int4 s4 = *(const int4*)&oei[e0];
        #pragma unroll
        for (int j = 0; j < 4; ++j) {
            int d = (&d4.x)[j];
            int pos = atomicAdd(&ocnt[d], 1);
            if (pos < CAP_) ocolsrc[(d << 5) + pos] = (&s4.x)[j];
        }
    } else if (b < 1232) {
        int idx = b - 1040, mat = idx >> 4, chunk = idx & 15;
        int arr = mat / 3, layer = mat % 3;
        const float* W = (arr == 0 ? Wr1 : arr == 1 ? Wn1 : arr == 2 ? Wr2 : Wn2) + (size_t)layer * 16384;
        h16* outh = wt + (size_t)mat * 16384;
        int base = chunk * 1024;
        for (int i = t; i < 1024; i += 256) {
            int id = base + i;
            int k = id >> 7, n = id & 127;
            outh[n * 128 + k] = (h16)W[id];
        }
    } else if (b < 1328) {
        int idx = b - 1232, m = idx >> 4, chunk = idx & 15;
        int layer = m >> 1, which = m & 1;
        const float* W = (which ? Wk : Wq) + (size_t)layer * 16384;
        h16* o = wqkt + (size_t)m * 16384;
        int base = chunk * 1024;
        for (int i = t; i < 1024; i += 256) {
            int id = base + i;
            int k = id >> 7, n = id & 127;
            o[n * 128 + k] = (h16)W[id];
        }
    } else {
        int gs = b - 1328;
        int cg = t & 31, rg = t >> 5;
        int c4 = cg * 4;
        float4 ssum = make_float4(0.f, 0.f, 0.f, 0.f);
        for (int n = rg; n < 32; n += 8) {
            size_t tt = (size_t)gs * 32 + n;
            float4 v = *(const float4*)&x0[tt * 128 + c4];
            half4 o; o[0] = (h16)v.x; o[1] = (h16)v.y; o[2] = (h16)v.z; o[3] = (h16)v.w;
            *(half4*)&xh[tt * 128 + c4] = o;
            ssum.x += v.x; ssum.y += v.y; ssum.z += v.z; ssum.w += v.w;
        }
        *(float4*)&red[rg][c4] = ssum;
        __syncthreads();
        if (rg == 0) {
            float4 s = make_float4(0.f, 0.f, 0.f, 0.f);
            #pragma unroll
            for (int r = 0; r < 8; ++r) {
                float4 v = *(float4*)&red[r][c4];
                s.x += v.x; s.y += v.y; s.z += v.z; s.w += v.w;
            }
            const float inv = 1.f / 32.f;
            half4 o; o[0] = (h16)(s.x*inv); o[1] = (h16)(s.y*inv); o[2] = (h16)(s.z*inv); o[3] = (h16)(s.w*inv);
            *(half4*)&subh[(size_t)gs * 128 + c4] = o;
        }
    }
}

// ================= bucketed aggregation (T + TO merged), SINGLE pass, full row =================
// 16 nodes/block, 16 lanes x half8 = full 256B row per node; bucket ints read once.
// blocks [0,8192): T gather from xh; [8192,8448): TO gather from xat.
__global__ __launch_bounds__(256) void k_agg2(
    const h16* __restrict__ xh, const int* __restrict__ cnt, const int* __restrict__ colsrc,
    h16* __restrict__ agg,
    const h16* __restrict__ xat, const int* __restrict__ ocnt, const int* __restrict__ ocolsrc,
    h16* __restrict__ agg2)
{
    const int bx = blockIdx.x;
    const h16* src; const int* cptr; const int* bsrc; h16* dst; int nid;
    if (bx < 8192) { src = xh;  cptr = cnt;  bsrc = colsrc;  dst = agg;  nid = bx * 16 + (threadIdx.x >> 4); }
    else           { src = xat; cptr = ocnt; bsrc = ocolsrc; dst = agg2; nid = (bx - 8192) * 16 + (threadIdx.x >> 4); }
    const int foff = (threadIdx.x & 15) * 8;
    int n = cptr[nid]; n = (n > CAP_) ? CAP_ : n;
    const int* __restrict__ bucket = bsrc + ((size_t)nid << 5);
    float acc[8] = {0.f,0.f,0.f,0.f,0.f,0.f,0.f,0.f};
    const int n4 = n & ~3;
    int e = 0;
    for (; e < n4; e += 4) {
        int4 s4 = *(const int4*)&bucket[e];
        half8 v0 = *(const half8*)&src[(size_t)s4.x * 128 + foff];
        half8 v1 = *(const half8*)&src[(size_t)s4.y * 128 + foff];
        half8 v2 = *(const half8*)&src[(size_t)s4.z * 128 + foff];
        half8 v3 = *(const half8*)&src[(size_t)s4.w * 128 + foff];
        #pragma unroll
        for (int q = 0; q < 8; ++q)
            acc[q] += ((float)v0[q] + (float)v1[q]) + ((float)v2[q] + (float)v3[q]);
    }
    for (; e < n; ++e) {
        int s = bucket[e];
        half8 v = *(const half8*)&src[(size_t)s * 128 + foff];
        #pragma unroll
        for (int q = 0; q < 8; ++q) acc[q] += (float)v[q];
    }
    half8 o;
    #pragma unroll
    for (int j = 0; j < 8; ++j) o[j] = (h16)acc[j];
    *(half8*)&dst[(size_t)nid * 128 + foff] = o;
}

// ================= per-graph attention: q/k MFMA -> softmax -> head-mean -> x_atten =================
__global__ __launch_bounds__(256) void k_attn(
    const h16* __restrict__ subh, const h16* __restrict__ wqkt_l,
    const float* __restrict__ bql, const float* __restrict__ bkl,
    const h16* __restrict__ xh, float* __restrict__ heat, h16* __restrict__ xat)
{
    __shared__ __align__(16) char smem[25600];
    const int tid = threadIdx.x;
    const int g = blockIdx.x;
    h16* aF = (h16*)smem;                   // 512 frag units x 8 h16 = 8KB
    h16* qkT = (h16*)(smem + 8192);         // [mat][n(128)][34] fp16
    float* attn_s = (float*)smem;           // alias over aF after GEMM phase
    #pragma unroll
    for (int it = 0; it < 2; ++it) {
        int u = tid + it * 256;
        int kq = u >> 6, l = u & 63;
        int m = l & 31, ko = kq * 16 + (l >> 5) * 8;
        *(half8*)&aF[u * 8] = *(const half8*)&subh[((size_t)g * 32 + m) * 128 + ko];
    }
    __syncthreads();
    const int w = tid >> 6, lane = tid & 63, lm = lane & 31, lh = lane >> 5;
    const int mat = w & 1, ntp = (w >> 1) * 2;
    const h16* Wt = wqkt_l + (size_t)mat * 16384;
    const float* bias = mat ? bkl : bql;
    f32x16 a0, a1;
    #pragma unroll
    for (int r = 0; r < 16; ++r) { a0[r] = 0.f; a1[r] = 0.f; }
    #pragma unroll
    for (int kq = 0; kq < 8; ++kq) {
        half8 av = *(half8*)&aF[(kq * 64 + lane) * 8];
        half8 b0 = *(const half8*)&Wt[(size_t)(ntp * 32 + lm) * 128 + kq * 16 + lh * 8];
        half8 b1 = *(const half8*)&Wt[(size_t)((ntp + 1) * 32 + lm) * 128 + kq * 16 + lh * 8];
        a0 = __builtin_amdgcn_mfma_f32_32x32x16_f16(av, b0, a0, 0, 0, 0);
        a1 = __builtin_amdgcn_mfma_f32_32x32x16_f16(av, b1, a1, 0, 0, 0);
    }
    __syncthreads();
    #pragma unroll
    for (int ti = 0; ti < 2; ++ti) {
        int n = (ntp + ti) * 32 + lm;
        float bn = bias[n];
        #pragma unroll
        for (int r = 0; r < 16; ++r) {
            int s = (r & 3) + 8 * (r >> 2) + 4 * lh;
            float v = (ti ? a1[r] : a0[r]) + bn;
            qkT[(mat * 128 + n) * 34 + s] = (h16)v;
        }
    }
    for (int i = tid; i < 1024; i += 256) attn_s[i] = 0.f;
    __syncthreads();
    if (tid < 128) {
        int h = tid >> 5, i = tid & 31;
        float qreg[32];
        #pragma unroll
        for (int d = 0; d < 32; ++d) qreg[d] = (float)qkT[(h * 32 + d) * 34 + i];
        float sc[32];
        const float scale = 0.17677669529663687f; // 1/sqrt(32)
        float mx = -1e30f;
        #pragma unroll
        for (int j = 0; j < 32; ++j) {
            float d = 0.f;
            #pragma unroll
            for (int d0 = 0; d0 < 32; ++d0) d += qreg[d0] * (float)qkT[(128 + h * 32 + d0) * 34 + j];
            d *= scale;
            sc[j] = d;
            mx = fmaxf(mx, d);
        }
        float ssum = 0.f;
        #pragma unroll
        for (int j = 0; j < 32; ++j) { float ee = __expf(sc[j] - mx); sc[j] = ee; ssum += ee; }
        float inv = 0.25f / ssum;  // head-mean folded in
        #pragma unroll
        for (int j = 0; j < 32; ++j) atomicAdd(&attn_s[i * 32 + j], sc[j] * inv);
    }
    __syncthreads();
    if (heat != nullptr && g == 127) {
        for (int idx = tid; idx < 1024; idx += 256) heat[idx] = attn_s[idx];
    }
    {
        int c4 = (tid & 31) * 4;
        int ng = tid >> 5;
        for (int n = ng; n < 32; n += 8) {
            float ax = 0.f, ay = 0.f, az = 0.f, aw = 0.f;
            #pragma unroll
            for (int s = 0; s < 32; ++s) {
                float a = attn_s[s * 32 + n];
                half4 xv = *(const half4*)&xh[(((size_t)g * 32 + s) * 32 + n) * 128 + c4];
                ax += a * (float)xv[0]; ay += a * (float)xv[1];
                az += a * (float)xv[2]; aw += a * (float)xv[3];
            }
            half4 o; o[0] = (h16)ax; o[1] = (h16)ay; o[2] = (h16)az; o[3] = (h16)aw;
            *(half4*)&xat[((size_t)g * 32 + n) * 128 + c4] = o;
        }
    }
}

// ================= merged MFMA GraphConv (T branch | TO branch) + BN stats =================
__global__ __launch_bounds__(256) void k_convs(
    const h16* __restrict__ xT, const h16* __restrict__ aggT,
    const h16* __restrict__ xO, const h16* __restrict__ aggO,
    const h16* __restrict__ wt, int layer,
    const float* __restrict__ b1l, const float* __restrict__ b2l,
    h16* __restrict__ h1, h16* __restrict__ h2, float* __restrict__ stats)
{
    __shared__ h16 lsA[4096];
    __shared__ h16 lsB[4096];
    __shared__ float csum[128], csq[128];
    const int tid = threadIdx.x;
    const h16 *A0, *A1, *W0, *W1; const float* bias; h16* outp; float *gsum, *gsq; size_t row0;
    if (blockIdx.x < 1024) {
        A0 = xT; A1 = aggT;
        W0 = wt + (size_t)(0 * 3 + layer) * 16384;
        W1 = wt + (size_t)(1 * 3 + layer) * 16384;
        bias = b1l; outp = h1; gsum = stats; gsq = stats + 128;
        row0 = (size_t)blockIdx.x * 128;
    } else {
        A0 = xO; A1 = aggO;
        W0 = wt + (size_t)(2 * 3 + layer) * 16384;
        W1 = wt + (size_t)(3 * 3 + layer) * 16384;
        bias = b2l; outp = h2; gsum = stats + 256; gsq = stats + 384;
        row0 = (size_t)(blockIdx.x - 1024) * 128;
    }
    if (tid < 128) { csum[tid] = 0.f; csq[tid] = 0.f; }
    const int w = tid >> 6, lane = tid & 63, lm = lane & 31, lh = lane >> 5;
    const int mbase = (w & 1) * 64, nbase = (w >> 1) * 64;
    f32x16 acc[2][2];
    #pragma unroll
    for (int mi = 0; mi < 2; ++mi)
        #pragma unroll
        for (int ni = 0; ni < 2; ++ni)
            #pragma unroll
            for (int r = 0; r < 16; ++r) acc[mi][ni][r] = 0.f;

    for (int p = 0; p < 2; ++p) {
        const h16* A = p ? A1 : A0;
        const h16* B = p ? W1 : W0;
        for (int kc = 0; kc < 4; ++kc) {
            __syncthreads();
            #pragma unroll
            for (int it = 0; it < 2; ++it) {
                int u = tid + it * 256;
                int m = u & 127, ch = u >> 7;
                *(half8*)&lsA[u * 8] = *(const half8*)&A[(row0 + m) * 128 + kc * 32 + ch * 8];
                *(half8*)&lsB[u * 8] = *(const half8*)&B[(size_t)m * 128 + kc * 32 + ch * 8];
            }
            __syncthreads();
            #pragma unroll
            for (int c = 0; c < 2; ++c) {
                const int base = (2 * c + lh) * 128;
                half8 a0 = *(half8*)&lsA[(base + mbase + lm) * 8];
                half8 a1 = *(half8*)&lsA[(base + mbase + 32 + lm) * 8];
                half8 b0 = *(half8*)&lsB[(base + nbase + lm) * 8];
                half8 b1 = *(half8*)&lsB[(base + nbase + 32 + lm) * 8];
                acc[0][0] = __builtin_amdgcn_mfma_f32_32x32x16_f16(a0, b0, acc[0][0], 0, 0, 0);
                acc[0][1] = __builtin_amdgcn_mfma_f32_32x32x16_f16(a0, b1, acc[0][1], 0, 0, 0);
                acc[1][0] = __builtin_amdgcn_mfma_f32_32x32x16_f16(a1, b0, acc[1][0], 0, 0, 0);
                acc[1][1] = __builtin_amdgcn_mfma_f32_32x32x16_f16(a1, b1, acc[1][1], 0, 0, 0);
            }
        }
    }
    #pragma unroll
    for (int ni = 0; ni < 2; ++ni) {
        int col = nbase + ni * 32 + lm;
        float bcol = bias[col];
        float s = 0.f, q = 0.f;
        #pragma unroll
        for (int mi = 0; mi < 2; ++mi) {
            #pragma unroll
            for (int r = 0; r < 16; ++r) {
                int row = mbase + mi * 32 + (r & 3) + 8 * (r >> 2) + 4 * lh;
                float o = acc[mi][ni][r] + bcol;
                outp[(row0 + row) * 128 + col] = (h16)o;
                s += o; q += o * o;
            }
        }
        atomicAdd(&csum[col], s);
        atomicAdd(&csq[col], q);
    }
    __syncthreads();
    if (tid < 128) atomicAdd(&gsum[tid], csum[tid]);
    else           atomicAdd(&gsq[tid - 128], csq[tid - 128]);
}

// ================= x = relu(BN1(h1)+BN2(h2)); fused BN-finalize + next submean =================
__global__ __launch_bounds__(256) void k_update(
    const h16* __restrict__ hpre, const h16* __restrict__ h2pre,
    const float* __restrict__ stats,
    const float* __restrict__ g1, const float* __restrict__ be1,
    const float* __restrict__ g2, const float* __restrict__ be2,
    h16* __restrict__ x, h16* __restrict__ subh)
{
    __shared__ float sA[128], hA[128], sB[128], hB[128];
    __shared__ float red[8][132];
    int gs = blockIdx.x, g = gs >> 5, tid = threadIdx.x;
    if (tid < 128) {
        float mu = stats[tid] * (1.f / T_);
        float var = stats[128 + tid] * (1.f / T_) - mu * mu;
        float sc = g1[tid] * rsqrtf(var + 1e-5f);
        sA[tid] = sc; hA[tid] = be1[tid] - mu * sc;
    } else {
        int c = tid - 128;
        float mu = stats[256 + c] * (1.f / TO_);
        float var = stats[384 + c] * (1.f / TO_) - mu * mu;
        float sc = g2[c] * rsqrtf(var + 1e-5f);
        sB[c] = sc; hB[c] = be2[c] - mu * sc;
    }
    __syncthreads();
    int cg = tid & 31, ng = tid >> 5;
    int c4 = cg * 4;
    float4 ssum = make_float4(0.f, 0.f, 0.f, 0.f);
    for (int n = ng; n < 32; n += 8) {
        size_t t = (size_t)gs * 32 + n;
        half4 h1v = *(const half4*)&hpre[t * 128 + c4];
        half4 h2v = *(const half4*)&h2pre[((size_t)g * 32 + n) * 128 + c4];
        float o0 = fmaxf((float)h1v[0] * sA[c4+0] + hA[c4+0] + (float)h2v[0] * sB[c4+0] + hB[c4+0], 0.f);
        float o1 = fmaxf((float)h1v[1] * sA[c4+1] + hA[c4+1] + (float)h2v[1] * sB[c4+1] + hB[c4+1], 0.f);
        float o2 = fmaxf((float)h1v[2] * sA[c4+2] + hA[c4+2] + (float)h2v[2] * sB[c4+2] + hB[c4+2], 0.f);
        float o3 = fmaxf((float)h1v[3] * sA[c4+3] + hA[c4+3] + (float)h2v[3] * sB[c4+3] + hB[c4+3], 0.f);
        half4 o; o[0] = (h16)o0; o[1] = (h16)o1; o[2] = (h16)o2; o[3] = (h16)o3;
        *(half4*)&x[t * 128 + c4] = o;
        ssum.x += o0; ssum.y += o1; ssum.z += o2; ssum.w += o3;
    }
    *(float4*)&red[ng][c4] = ssum;
    __syncthreads();
    if (ng == 0) {
        float4 s = make_float4(0.f, 0.f, 0.f, 0.f);
        #pragma unroll
        for (int r = 0; r < 8; ++r) {
            float4 v = *(float4*)&red[r][c4];
            s.x += v.x; s.y += v.y; s.z += v.z; s.w += v.w;
        }
        const float inv = 1.f / 32.f;
        half4 o; o[0] = (h16)(s.x*inv); o[1] = (h16)(s.y*inv); o[2] = (h16)(s.z*inv); o[3] = (h16)(s.w*inv);
        *(half4*)&subh[(size_t)gs * 128 + c4] = o;
    }
}

// ================= final head =================
__global__ __launch_bounds__(256) void k_dense(const h16* __restrict__ subh, const float* __restrict__ Wf1,
    const float* __restrict__ bf1, const float* __restrict__ Wf2, const float* __restrict__ bf2,
    float* __restrict__ out)
{
    int g = blockIdx.x, tid = threadIdx.x;
    __shared__ float hgs[128];
    __shared__ float hid[256];
    if (tid < 128) {
        float s = 0.f;
        for (int ss = 0; ss < 32; ++ss) s += (float)subh[((size_t)g * 32 + ss) * 128 + tid];
        hgs[tid] = s * (1.f / 32.f);
    }
    __syncthreads();
    float a = bf1[tid];
    for (int k = 0; k < 128; ++k) a += hgs[k] * Wf1[k * 256 + tid];
    hid[tid] = fmaxf(a, 0.f);
    __syncthreads();
    if (tid < 10) {
        float o = bf2[tid];
        for (int k = 0; k < 256; ++k) o += hid[k] * Wf2[k * 10 + tid];
        out[g * 10 + tid] = o;
    }
}

extern "C" void kernel_launch(void* const* d_in, const int* in_sizes, int n_in,
                              void* d_out, int out_size, void* d_ws, size_t ws_size,
                              hipStream_t stream)
{
    (void)in_sizes; (void)n_in; (void)out_size; (void)ws_size;
    const float* x0  = (const float*)d_in[0];
    const int*   ei  = (const int*)d_in[1];
    const int*   oei = (const int*)d_in[2];
    const float* Wr1 = (const float*)d_in[3];
    const float* Wn1 = (const float*)d_in[4];
    const float* b1  = (const float*)d_in[5];
    const float* g1  = (const float*)d_in[6];
    const float* be1 = (const float*)d_in[7];
    const float* Wr2 = (const float*)d_in[8];
    const float* Wn2 = (const float*)d_in[9];
    const float* b2  = (const float*)d_in[10];
    const float* g2  = (const float*)d_in[11];
    const float* be2 = (const float*)d_in[12];
    const float* Wq  = (const float*)d_in[13];
    const float* bq  = (const float*)d_in[14];
    const float* Wk  = (const float*)d_in[15];
    const float* bk  = (const float*)d_in[16];
    const float* Wf1 = (const float*)d_in[17];
    const float* bf1 = (const float*)d_in[18];
    const float* Wf2 = (const float*)d_in[19];
    const float* bf2 = (const float*)d_in[20];
    float* out = (float*)d_out;

    char* w = (char*)d_ws;
    size_t off = 0;
    auto alloc = [&](size_t bytes) { void* p = w + off; off = (off + bytes + 255) & ~(size_t)255; return p; };
    h16* xh     = (h16*)alloc((size_t)T_ * D_ * 2);
    h16* aggh   = (h16*)alloc((size_t)T_ * D_ * 2);   // aliased as h1pre (block-local RAW safe)
    h16* agg2   = (h16*)alloc((size_t)TO_ * D_ * 2);  // aliased as h2pre
    h16* xat    = (h16*)alloc((size_t)TO_ * D_ * 2);
    h16* wt     = (h16*)alloc((size_t)12 * 16384 * 2);
    h16* wqkt   = (h16*)alloc((size_t)6 * 16384 * 2);
    h16* subh   = (h16*)alloc((size_t)G_ * S_ * D_ * 2);
    // zero-init region: cnt | ocnt | stats(3 layers x 512)
    int* cnt     = (int*)alloc((size_t)(T_ + TO_) * 4 + 1536 * 4);
    int* ocnt    = cnt + T_;
    float* stats = (float*)(cnt + T_ + TO_);
    int* colsrc  = (int*)alloc((size_t)T_ * CAP_ * 4);    // 16 MB buckets
    int* ocolsrc = (int*)alloc((size_t)TO_ * CAP_ * 4);

    h16* h1pre = aggh;
    h16* h2pre = agg2;

    hipMemsetAsync(cnt, 0, (size_t)(T_ + TO_) * 4 + 1536 * 4, stream);
    k_prep<<<5424, 256, 0, stream>>>(ei, oei, Wr1, Wn1, Wr2, Wn2, Wq, Wk, x0,
                                     cnt, ocnt, colsrc, ocolsrc, wt, wqkt, xh, subh);

    for (int i = 0; i < 3; ++i) {
        // attention first: produces xat so the merged gather can do T and TO together
        k_attn<<<G_, 256, 0, stream>>>(subh, wqkt + (size_t)i * 2 * 16384,
            bq + i * D_, bk + i * D_, xh,
            (i == 2) ? (out + G_ * NTASK_) : nullptr, xat);
        k_agg2<<<8448, 256, 0, stream>>>(xh, cnt, colsrc, aggh,
                                         xat, ocnt, ocolsrc, agg2);
        k_convs<<<1056, 256, 0, stream>>>(xh, aggh, xat, agg2, wt, i,
            b1 + i * D_, b2 + i * D_, h1pre, h2pre, stats + i * 512);
        k_update<<<G_ * S_, 256, 0, stream>>>(h1pre, h2pre, stats + i * 512,
            g1 + i * D_, be1 + i * D_, g2 + i * D_, be2 + i * D_, xh, subh);
    }
    k_dense<<<G_, 256, 0, stream>>>(subh, Wf1, bf1, Wf2, bf2, out);
}